// Round 1
// baseline (2684.412 us; speedup 1.0000x reference)
//
#include <hip/hip_runtime.h>

#define NN 100000
#define NE 1600000
#define NH 128
#define N_MID 9

// ---------------- CSR build ----------------

__global__ __launch_bounds__(256) void count_k(const int* __restrict__ edst, int* __restrict__ cnt) {
    int e = blockIdx.x * 256 + threadIdx.x;
    if (e < NE) atomicAdd(&cnt[edst[e]], 1);
}

// single block, 1024 threads: exclusive scan of cnt[0..NN) -> rp[0..NN], cursor copy
__global__ __launch_bounds__(1024) void scan_k(const int* __restrict__ cnt, int* __restrict__ rp,
                                               int* __restrict__ cur) {
    __shared__ int tsum[1024];
    const int tid = threadIdx.x;
    const int per = (NN + 1023) / 1024;  // 98
    int beg = tid * per;
    int end = beg + per; if (end > NN) end = NN;
    int s = 0;
    for (int i = beg; i < end && i >= 0; i++) s += cnt[i];
    tsum[tid] = s;
    __syncthreads();
    // inclusive Hillis-Steele scan
    for (int off = 1; off < 1024; off <<= 1) {
        int v = (tid >= off) ? tsum[tid - off] : 0;
        __syncthreads();
        tsum[tid] += v;
        __syncthreads();
    }
    int run = (tid == 0) ? 0 : tsum[tid - 1];
    for (int i = beg; i < end; i++) {
        rp[i] = run;
        cur[i] = run;
        run += cnt[i];
    }
    if (tid == 1023) rp[NN] = tsum[1023];
}

__global__ __launch_bounds__(256) void scatter_k(const int* __restrict__ esrc, const int* __restrict__ edst,
                                                 const float* __restrict__ av, int* __restrict__ cur,
                                                 int2* __restrict__ rec) {
    int e = blockIdx.x * 256 + threadIdx.x;
    if (e < NE) {
        int d = edst[e];
        int p = atomicAdd(&cur[d], 1);
        rec[p] = make_int2(esrc[e], __float_as_int(av[e]));
    }
}

// ---------------- dense GEMM: S = X @ W, X [nrows,128], W [128,128] ----------------

__global__ __launch_bounds__(256) void gemm128(const float* __restrict__ X, const float* __restrict__ W,
                                               float* __restrict__ S, int nrows) {
    __shared__ float xs[128 * 132];   // x tile, row stride 132 (pad: bank-spread)
    __shared__ float wsh[128 * 128];  // W row-major
    const int tid = threadIdx.x;
    const int row0 = blockIdx.x * 128;

    {   // load W: 16384 floats = 4096 float4
        const float4* W4 = (const float4*)W;
        float4* d = (float4*)wsh;
#pragma unroll
        for (int i = 0; i < 16; i++) d[tid + 256 * i] = W4[tid + 256 * i];
    }
    // load X tile: 128 rows x 32 float4
    for (int i = tid; i < 128 * 32; i += 256) {
        int r = i >> 5, c = i & 31;
        int gr = row0 + r;
        float4 v = make_float4(0.f, 0.f, 0.f, 0.f);
        if (gr < nrows) v = ((const float4*)X)[gr * 32 + c];
        *(float4*)&xs[r * 132 + c * 4] = v;
    }
    __syncthreads();

    const int tr = tid >> 4;        // 0..15
    const int c0 = (tid & 15) * 8;  // col block
    float acc[8][8];
#pragma unroll
    for (int i = 0; i < 8; i++)
#pragma unroll
        for (int j = 0; j < 8; j++) acc[i][j] = 0.f;

    for (int k = 0; k < 128; k += 4) {
        float4 xv[8];
#pragma unroll
        for (int i = 0; i < 8; i++) xv[i] = *(const float4*)&xs[(tr + 16 * i) * 132 + k];
#pragma unroll
        for (int kk = 0; kk < 4; kk++) {
            float4 w0 = *(const float4*)&wsh[(k + kk) * 128 + c0];
            float4 w1 = *(const float4*)&wsh[(k + kk) * 128 + c0 + 4];
#pragma unroll
            for (int i = 0; i < 8; i++) {
                float xk = (kk == 0) ? xv[i].x : (kk == 1) ? xv[i].y : (kk == 2) ? xv[i].z : xv[i].w;
                acc[i][0] = fmaf(xk, w0.x, acc[i][0]);
                acc[i][1] = fmaf(xk, w0.y, acc[i][1]);
                acc[i][2] = fmaf(xk, w0.z, acc[i][2]);
                acc[i][3] = fmaf(xk, w0.w, acc[i][3]);
                acc[i][4] = fmaf(xk, w1.x, acc[i][4]);
                acc[i][5] = fmaf(xk, w1.y, acc[i][5]);
                acc[i][6] = fmaf(xk, w1.z, acc[i][6]);
                acc[i][7] = fmaf(xk, w1.w, acc[i][7]);
            }
        }
    }
#pragma unroll
    for (int i = 0; i < 8; i++) {
        int gr = row0 + tr + 16 * i;
        if (gr < nrows) {
            *(float4*)&S[gr * 128 + c0] = make_float4(acc[i][0], acc[i][1], acc[i][2], acc[i][3]);
            *(float4*)&S[gr * 128 + c0 + 4] = make_float4(acc[i][4], acc[i][5], acc[i][6], acc[i][7]);
        }
    }
}

// ---------------- SPMM (CSR, wave per node) + bias + relu ----------------

__global__ __launch_bounds__(256) void spmm_bias_relu(const float* __restrict__ S, const int2* __restrict__ rec,
                                                      const int* __restrict__ rp, const float* __restrict__ bias,
                                                      float* __restrict__ Xo) {
    int node = blockIdx.x * 4 + (threadIdx.x >> 6);
    if (node >= NN) return;
    int lane = threadIdx.x & 63;
    int beg = rp[node], end = rp[node + 1];
    float ax = 0.f, ay = 0.f;
    for (int e = beg; e < end; e++) {
        int2 r = rec[e];
        float v = __int_as_float(r.y);
        float2 s = *(const float2*)&S[r.x * 128 + lane * 2];
        ax = fmaf(v, s.x, ax);
        ay = fmaf(v, s.y, ay);
    }
    float2 b = *(const float2*)&bias[lane * 2];
    float2 o;
    o.x = fmaxf(ax + b.x, 0.f);
    o.y = fmaxf(ay + b.y, 0.f);
    *(float2*)&Xo[node * 128 + lane * 2] = o;
}

// ---------------- layer 10 ----------------

__global__ __launch_bounds__(256) void dot128(const float* __restrict__ X, const float* __restrict__ w,
                                              float* __restrict__ s10) {
    int node = blockIdx.x * 4 + (threadIdx.x >> 6);
    if (node >= NN) return;
    int lane = threadIdx.x & 63;
    float2 x = *(const float2*)&X[node * 128 + lane * 2];
    float2 ww = *(const float2*)&w[lane * 2];
    float p = x.x * ww.x + x.y * ww.y;
#pragma unroll
    for (int off = 32; off; off >>= 1) p += __shfl_down(p, off, 64);
    if (lane == 0) s10[node] = p;
}

__global__ __launch_bounds__(256) void spmm_scalar(const float* __restrict__ s10, const int2* __restrict__ rec,
                                                   const int* __restrict__ rp, const float* __restrict__ b10,
                                                   float* __restrict__ o10) {
    int node = blockIdx.x * 256 + threadIdx.x;
    if (node >= NN) return;
    int beg = rp[node], end = rp[node + 1];
    float a = 0.f;
    for (int e = beg; e < end; e++) {
        int2 r = rec[e];
        a = fmaf(__int_as_float(r.y), s10[r.x], a);
    }
    o10[node] = a + b10[0];
}

// ---------------- log_softmax ----------------

__global__ __launch_bounds__(1024) void lsm_reduce(const float* __restrict__ v, float* __restrict__ cout) {
    __shared__ float red[1024];
    const int tid = threadIdx.x;
    float m = -3.402823466e+38f;
    for (int i = tid; i < NN; i += 1024) m = fmaxf(m, v[i]);
    red[tid] = m;
    __syncthreads();
    for (int s = 512; s > 0; s >>= 1) {
        if (tid < s) red[tid] = fmaxf(red[tid], red[tid + s]);
        __syncthreads();
    }
    float mm = red[0];
    __syncthreads();
    float sum = 0.f;
    for (int i = tid; i < NN; i += 1024) sum += expf(v[i] - mm);
    red[tid] = sum;
    __syncthreads();
    for (int s = 512; s > 0; s >>= 1) {
        if (tid < s) red[tid] += red[tid + s];
        __syncthreads();
    }
    if (tid == 0) cout[0] = mm + logf(red[0]);
}

__global__ __launch_bounds__(256) void lsm_write(const float* __restrict__ o10, const float* __restrict__ c,
                                                 float* __restrict__ out) {
    int i = blockIdx.x * 256 + threadIdx.x;
    if (i < NN) out[i] = o10[i] - c[0];
}

// ---------------- launch ----------------

extern "C" void kernel_launch(void* const* d_in, const int* in_sizes, int n_in,
                              void* d_out, int out_size, void* d_ws, size_t ws_size,
                              hipStream_t stream) {
    const float* features = (const float*)d_in[0];
    const float* adj_vals = (const float*)d_in[1];
    const float* Ws       = (const float*)d_in[2];
    const float* bs       = (const float*)d_in[3];
    const float* W10      = (const float*)d_in[4];
    const float* b10      = (const float*)d_in[5];
    const int*   esrc     = (const int*)d_in[6];
    const int*   edst     = (const int*)d_in[7];
    float* out = (float*)d_out;

    char* ws = (char*)d_ws;
    const size_t SZX = (size_t)NN * NH * 4;      // 51.2 MB
    float* S   = (float*)(ws);
    float* xA  = (float*)(ws + SZX);
    float* xB  = (float*)(ws + 2 * SZX);
    int2*  rec = (int2*)(ws + 3 * SZX);          // 12.8 MB
    int*   cnt = (int*)(ws + 3 * SZX + (size_t)NE * 8);
    int*   rp  = cnt + NN;                       // NN+1 ints
    int*   cur = rp + NN + 1;
    float* s10 = (float*)(cur + NN);
    float* o10 = s10 + NN;
    float* cbuf = o10 + NN;

    // CSR build (per call; deterministic partition, order within node may vary -> fp-tolerant)
    hipMemsetAsync(cnt, 0, (size_t)NN * 4, stream);
    count_k<<<(NE + 255) / 256, 256, 0, stream>>>(edst, cnt);
    scan_k<<<1, 1024, 0, stream>>>(cnt, rp, cur);
    scatter_k<<<(NE + 255) / 256, 256, 0, stream>>>(esrc, edst, adj_vals, cur, rec);

    const float* xin = features;
    float* xout = xA;
    for (int l = 0; l < N_MID; l++) {
        gemm128<<<(NN + 127) / 128, 256, 0, stream>>>(xin, Ws + (size_t)l * NH * NH, S, NN);
        spmm_bias_relu<<<NN / 4, 256, 0, stream>>>(S, rec, rp, bs + (size_t)l * NH, xout);
        xin = xout;
        xout = (xout == xA) ? xB : xA;
    }

    dot128<<<NN / 4, 256, 0, stream>>>(xin, W10, s10);
    spmm_scalar<<<(NN + 255) / 256, 256, 0, stream>>>(s10, rec, rp, b10, o10);
    lsm_reduce<<<1, 1024, 0, stream>>>(o10, cbuf);
    lsm_write<<<(NN + 255) / 256, 256, 0, stream>>>(o10, cbuf, out);
}

// Round 2
// 2442.691 us; speedup vs baseline: 1.0990x; 1.0990x over previous
//
#include <hip/hip_runtime.h>
#include <float.h>

#define NN 100000
#define NE 1600000
#define NH 128
#define N_MID 9

#define SCAN_NB ((NN + 255) / 256)   // 391

// ---------------- CSR build ----------------

__global__ __launch_bounds__(256) void count_k(const int* __restrict__ edst, int* __restrict__ cnt) {
    int e = blockIdx.x * 256 + threadIdx.x;
    if (e < NE) atomicAdd(&cnt[edst[e]], 1);
}

// hierarchical scan, stage 1: per-block sums of cnt
__global__ __launch_bounds__(256) void scan_part(const int* __restrict__ cnt, int* __restrict__ bsum) {
    __shared__ int s[256];
    int i = blockIdx.x * 256 + threadIdx.x;
    int v = (i < NN) ? cnt[i] : 0;
    s[threadIdx.x] = v;
    __syncthreads();
    for (int off = 128; off; off >>= 1) {
        if (threadIdx.x < off) s[threadIdx.x] += s[threadIdx.x + off];
        __syncthreads();
    }
    if (threadIdx.x == 0) bsum[blockIdx.x] = s[0];
}

// stage 2: exclusive scan of the 391 block sums (single small block)
__global__ __launch_bounds__(512) void scan_top(int* __restrict__ bsum) {
    __shared__ int s[512];
    int tid = threadIdx.x;
    int v = (tid < SCAN_NB) ? bsum[tid] : 0;
    s[tid] = v;
    __syncthreads();
    for (int off = 1; off < 512; off <<= 1) {
        int t = (tid >= off) ? s[tid - off] : 0;
        __syncthreads();
        s[tid] += t;
        __syncthreads();
    }
    if (tid < SCAN_NB) bsum[tid] = s[tid] - v;  // exclusive
}

// stage 3: per-block exclusive scan + offset -> rp, cur
__global__ __launch_bounds__(256) void scan_final(const int* __restrict__ cnt, const int* __restrict__ bsum,
                                                  int* __restrict__ rp, int* __restrict__ cur) {
    __shared__ int s[256];
    int i = blockIdx.x * 256 + threadIdx.x;
    int v = (i < NN) ? cnt[i] : 0;
    s[threadIdx.x] = v;
    __syncthreads();
    for (int off = 1; off < 256; off <<= 1) {
        int t = (threadIdx.x >= off) ? s[threadIdx.x - off] : 0;
        __syncthreads();
        s[threadIdx.x] += t;
        __syncthreads();
    }
    int excl = s[threadIdx.x] - v + bsum[blockIdx.x];
    if (i < NN) { rp[i] = excl; cur[i] = excl; }
    if (i == NN - 1) rp[NN] = excl + v;
}

__global__ __launch_bounds__(256) void scatter_k(const int* __restrict__ esrc, const int* __restrict__ edst,
                                                 const float* __restrict__ av, int* __restrict__ cur,
                                                 int2* __restrict__ rec) {
    int e = blockIdx.x * 256 + threadIdx.x;
    if (e < NE) {
        int d = edst[e];
        int p = atomicAdd(&cur[d], 1);
        rec[p] = make_int2(esrc[e], __float_as_int(av[e]));
    }
}

// ---------------- dense GEMM: S = X @ W, X [nrows,128], W [128,128] ----------------

__global__ __launch_bounds__(256) void gemm128(const float* __restrict__ X, const float* __restrict__ W,
                                               float* __restrict__ S, int nrows) {
    __shared__ float xs[128 * 132];   // x tile, row stride 132 (pad: bank-spread)
    __shared__ float wsh[128 * 128];  // W row-major
    const int tid = threadIdx.x;
    const int row0 = blockIdx.x * 128;

    {   // load W: 16384 floats = 4096 float4
        const float4* W4 = (const float4*)W;
        float4* d = (float4*)wsh;
#pragma unroll
        for (int i = 0; i < 16; i++) d[tid + 256 * i] = W4[tid + 256 * i];
    }
    // load X tile: 128 rows x 32 float4
    for (int i = tid; i < 128 * 32; i += 256) {
        int r = i >> 5, c = i & 31;
        int gr = row0 + r;
        float4 v = make_float4(0.f, 0.f, 0.f, 0.f);
        if (gr < nrows) v = ((const float4*)X)[gr * 32 + c];
        *(float4*)&xs[r * 132 + c * 4] = v;
    }
    __syncthreads();

    const int tr = tid >> 4;        // 0..15
    const int c0 = (tid & 15) * 8;  // col block
    float acc[8][8];
#pragma unroll
    for (int i = 0; i < 8; i++)
#pragma unroll
        for (int j = 0; j < 8; j++) acc[i][j] = 0.f;

    for (int k = 0; k < 128; k += 4) {
        float4 xv[8];
#pragma unroll
        for (int i = 0; i < 8; i++) xv[i] = *(const float4*)&xs[(tr + 16 * i) * 132 + k];
#pragma unroll
        for (int kk = 0; kk < 4; kk++) {
            float4 w0 = *(const float4*)&wsh[(k + kk) * 128 + c0];
            float4 w1 = *(const float4*)&wsh[(k + kk) * 128 + c0 + 4];
#pragma unroll
            for (int i = 0; i < 8; i++) {
                float xk = (kk == 0) ? xv[i].x : (kk == 1) ? xv[i].y : (kk == 2) ? xv[i].z : xv[i].w;
                acc[i][0] = fmaf(xk, w0.x, acc[i][0]);
                acc[i][1] = fmaf(xk, w0.y, acc[i][1]);
                acc[i][2] = fmaf(xk, w0.z, acc[i][2]);
                acc[i][3] = fmaf(xk, w0.w, acc[i][3]);
                acc[i][4] = fmaf(xk, w1.x, acc[i][4]);
                acc[i][5] = fmaf(xk, w1.y, acc[i][5]);
                acc[i][6] = fmaf(xk, w1.z, acc[i][6]);
                acc[i][7] = fmaf(xk, w1.w, acc[i][7]);
            }
        }
    }
#pragma unroll
    for (int i = 0; i < 8; i++) {
        int gr = row0 + tr + 16 * i;
        if (gr < nrows) {
            *(float4*)&S[gr * 128 + c0] = make_float4(acc[i][0], acc[i][1], acc[i][2], acc[i][3]);
            *(float4*)&S[gr * 128 + c0 + 4] = make_float4(acc[i][4], acc[i][5], acc[i][6], acc[i][7]);
        }
    }
}

// ---------------- SPMM (CSR, wave per node) + bias + relu ----------------

__global__ __launch_bounds__(256) void spmm_bias_relu(const float* __restrict__ S, const int2* __restrict__ rec,
                                                      const int* __restrict__ rp, const float* __restrict__ bias,
                                                      float* __restrict__ Xo) {
    int node = blockIdx.x * 4 + (threadIdx.x >> 6);
    if (node >= NN) return;
    int lane = threadIdx.x & 63;
    int beg = rp[node], end = rp[node + 1];
    float ax = 0.f, ay = 0.f;
    for (int e = beg; e < end; e++) {
        int2 r = rec[e];
        float v = __int_as_float(r.y);
        float2 s = *(const float2*)&S[r.x * 128 + lane * 2];
        ax = fmaf(v, s.x, ax);
        ay = fmaf(v, s.y, ay);
    }
    float2 b = *(const float2*)&bias[lane * 2];
    float2 o;
    o.x = fmaxf(ax + b.x, 0.f);
    o.y = fmaxf(ay + b.y, 0.f);
    *(float2*)&Xo[node * 128 + lane * 2] = o;
}

// ---------------- layer 10 ----------------

__global__ __launch_bounds__(256) void dot128(const float* __restrict__ X, const float* __restrict__ w,
                                              float* __restrict__ s10) {
    int node = blockIdx.x * 4 + (threadIdx.x >> 6);
    if (node >= NN) return;
    int lane = threadIdx.x & 63;
    float2 x = *(const float2*)&X[node * 128 + lane * 2];
    float2 ww = *(const float2*)&w[lane * 2];
    float p = x.x * ww.x + x.y * ww.y;
#pragma unroll
    for (int off = 32; off; off >>= 1) p += __shfl_down(p, off, 64);
    if (lane == 0) s10[node] = p;
}

__global__ __launch_bounds__(256) void spmm_scalar(const float* __restrict__ s10, const int2* __restrict__ rec,
                                                   const int* __restrict__ rp, const float* __restrict__ b10,
                                                   float* __restrict__ o10) {
    int node = blockIdx.x * 256 + threadIdx.x;
    if (node >= NN) return;
    int beg = rp[node], end = rp[node + 1];
    float a = 0.f;
    for (int e = beg; e < end; e++) {
        int2 r = rec[e];
        a = fmaf(__int_as_float(r.y), s10[r.x], a);
    }
    o10[node] = a + b10[0];
}

// ---------------- log_softmax (multi-block) ----------------

#define LSM_NB 240

__global__ __launch_bounds__(256) void lsm_max(const float* __restrict__ v, float* __restrict__ pmax) {
    __shared__ float s[256];
    float m = -FLT_MAX;
    for (int i = blockIdx.x * 256 + threadIdx.x; i < NN; i += LSM_NB * 256) m = fmaxf(m, v[i]);
    s[threadIdx.x] = m;
    __syncthreads();
    for (int off = 128; off; off >>= 1) {
        if (threadIdx.x < off) s[threadIdx.x] = fmaxf(s[threadIdx.x], s[threadIdx.x + off]);
        __syncthreads();
    }
    if (threadIdx.x == 0) pmax[blockIdx.x] = s[0];
}

__global__ __launch_bounds__(256) void lsm_sum(const float* __restrict__ v, const float* __restrict__ pmax,
                                               float* __restrict__ psum) {
    __shared__ float s[256];
    // every block reduces the 240 partial maxes itself (cheap, L2-hit)
    float m = -FLT_MAX;
    if (threadIdx.x < LSM_NB) m = pmax[threadIdx.x];
    s[threadIdx.x] = m;
    __syncthreads();
    for (int off = 128; off; off >>= 1) {
        if (threadIdx.x < off) s[threadIdx.x] = fmaxf(s[threadIdx.x], s[threadIdx.x + off]);
        __syncthreads();
    }
    float gm = s[0];
    __syncthreads();
    float sum = 0.f;
    for (int i = blockIdx.x * 256 + threadIdx.x; i < NN; i += LSM_NB * 256) sum += expf(v[i] - gm);
    s[threadIdx.x] = sum;
    __syncthreads();
    for (int off = 128; off; off >>= 1) {
        if (threadIdx.x < off) s[threadIdx.x] += s[threadIdx.x + off];
        __syncthreads();
    }
    if (threadIdx.x == 0) psum[blockIdx.x] = s[0];
}

__global__ __launch_bounds__(256) void lsm_fin(const float* __restrict__ pmax, const float* __restrict__ psum,
                                               float* __restrict__ c) {
    __shared__ float s[256];
    float m = -FLT_MAX, sum = 0.f;
    if (threadIdx.x < LSM_NB) { m = pmax[threadIdx.x]; sum = psum[threadIdx.x]; }
    s[threadIdx.x] = m;
    __syncthreads();
    for (int off = 128; off; off >>= 1) {
        if (threadIdx.x < off) s[threadIdx.x] = fmaxf(s[threadIdx.x], s[threadIdx.x + off]);
        __syncthreads();
    }
    float gm = s[0];
    __syncthreads();
    s[threadIdx.x] = sum;
    __syncthreads();
    for (int off = 128; off; off >>= 1) {
        if (threadIdx.x < off) s[threadIdx.x] += s[threadIdx.x + off];
        __syncthreads();
    }
    if (threadIdx.x == 0) c[0] = gm + logf(s[0]);
}

__global__ __launch_bounds__(256) void lsm_write(const float* __restrict__ o10, const float* __restrict__ c,
                                                 float* __restrict__ out) {
    int i = blockIdx.x * 256 + threadIdx.x;
    if (i < NN) out[i] = o10[i] - c[0];
}

// ---------------- launch ----------------

extern "C" void kernel_launch(void* const* d_in, const int* in_sizes, int n_in,
                              void* d_out, int out_size, void* d_ws, size_t ws_size,
                              hipStream_t stream) {
    const float* features = (const float*)d_in[0];
    const float* adj_vals = (const float*)d_in[1];
    const float* Ws       = (const float*)d_in[2];
    const float* bs       = (const float*)d_in[3];
    const float* W10      = (const float*)d_in[4];
    const float* b10      = (const float*)d_in[5];
    const int*   esrc     = (const int*)d_in[6];
    const int*   edst     = (const int*)d_in[7];
    float* out = (float*)d_out;

    char* ws = (char*)d_ws;
    const size_t SZX = (size_t)NN * NH * 4;      // 51.2 MB
    float* S   = (float*)(ws);
    float* xA  = (float*)(ws + SZX);
    float* xB  = (float*)(ws + 2 * SZX);
    int2*  rec = (int2*)(ws + 3 * SZX);          // 12.8 MB
    int*   cnt = (int*)(ws + 3 * SZX + (size_t)NE * 8);
    int*   rp  = cnt + NN;                       // NN+1 ints
    int*   cur = rp + NN + 1;
    int*   bsum = cur + NN;                      // SCAN_NB ints
    float* s10 = (float*)(bsum + SCAN_NB);
    float* o10 = s10 + NN;
    float* pmax = o10 + NN;                      // LSM_NB
    float* psum = pmax + LSM_NB;                 // LSM_NB
    float* cbuf = psum + LSM_NB;

    // CSR build (per call; deterministic partition, order within node may vary -> fp-tolerant)
    hipMemsetAsync(cnt, 0, (size_t)NN * 4, stream);
    count_k<<<(NE + 255) / 256, 256, 0, stream>>>(edst, cnt);
    scan_part<<<SCAN_NB, 256, 0, stream>>>(cnt, bsum);
    scan_top<<<1, 512, 0, stream>>>(bsum);
    scan_final<<<SCAN_NB, 256, 0, stream>>>(cnt, bsum, rp, cur);
    scatter_k<<<(NE + 255) / 256, 256, 0, stream>>>(esrc, edst, adj_vals, cur, rec);

    const float* xin = features;
    float* xout = xA;
    for (int l = 0; l < N_MID; l++) {
        gemm128<<<(NN + 127) / 128, 256, 0, stream>>>(xin, Ws + (size_t)l * NH * NH, S, NN);
        spmm_bias_relu<<<NN / 4, 256, 0, stream>>>(S, rec, rp, bs + (size_t)l * NH, xout);
        xin = xout;
        xout = (xout == xA) ? xB : xA;
    }

    dot128<<<NN / 4, 256, 0, stream>>>(xin, W10, s10);
    spmm_scalar<<<(NN + 255) / 256, 256, 0, stream>>>(s10, rec, rp, b10, o10);
    lsm_max<<<LSM_NB, 256, 0, stream>>>(o10, pmax);
    lsm_sum<<<LSM_NB, 256, 0, stream>>>(o10, pmax, psum);
    lsm_fin<<<1, 256, 0, stream>>>(pmax, psum, cbuf);
    lsm_write<<<(NN + 255) / 256, 256, 0, stream>>>(o10, cbuf, out);
}

// Round 3
// 1162.472 us; speedup vs baseline: 2.3092x; 2.1013x over previous
//
#include <hip/hip_runtime.h>
#include <float.h>

#define NN 100000
#define NE 1600000
#define NH 128
#define N_MID 9
#define SCAN_NB ((NN + 255) / 256)   // 391

typedef _Float16 half8 __attribute__((ext_vector_type(8)));
typedef _Float16 half2v __attribute__((ext_vector_type(2)));
typedef float f32x4 __attribute__((ext_vector_type(4)));

// ---------------- dtype prep ----------------

// features f32 -> f16, 8 elems/thread
__global__ __launch_bounds__(256) void conv_x(const float* __restrict__ in, _Float16* __restrict__ out) {
    int i = blockIdx.x * 256 + threadIdx.x;
    if (i >= NN * NH / 8) return;
    float4 v0 = ((const float4*)in)[i * 2];
    float4 v1 = ((const float4*)in)[i * 2 + 1];
    half8 o;
    o[0] = (_Float16)v0.x; o[1] = (_Float16)v0.y; o[2] = (_Float16)v0.z; o[3] = (_Float16)v0.w;
    o[4] = (_Float16)v1.x; o[5] = (_Float16)v1.y; o[6] = (_Float16)v1.z; o[7] = (_Float16)v1.w;
    ((half8*)out)[i] = o;
}

// Wt[l][n][k] = (f16) W[l][k][n]  (transpose so B columns are k-contiguous)
__global__ __launch_bounds__(256) void conv_w(const float* __restrict__ W, _Float16* __restrict__ Wt) {
    int i = blockIdx.x * 256 + threadIdx.x;
    if (i >= N_MID * NH * NH) return;
    int l = i / (NH * NH), rem = i % (NH * NH);
    int n = rem / NH, k = rem % NH;
    Wt[i] = (_Float16)W[l * NH * NH + k * NH + n];
}

// ---------------- CSR build ----------------

__global__ __launch_bounds__(256) void count_k(const int* __restrict__ edst, int* __restrict__ cnt) {
    int e = blockIdx.x * 256 + threadIdx.x;
    if (e < NE) atomicAdd(&cnt[edst[e]], 1);
}

__global__ __launch_bounds__(256) void scan_part(const int* __restrict__ cnt, int* __restrict__ bsum) {
    __shared__ int s[256];
    int i = blockIdx.x * 256 + threadIdx.x;
    int v = (i < NN) ? cnt[i] : 0;
    s[threadIdx.x] = v;
    __syncthreads();
    for (int off = 128; off; off >>= 1) {
        if (threadIdx.x < off) s[threadIdx.x] += s[threadIdx.x + off];
        __syncthreads();
    }
    if (threadIdx.x == 0) bsum[blockIdx.x] = s[0];
}

__global__ __launch_bounds__(512) void scan_top(int* __restrict__ bsum) {
    __shared__ int s[512];
    int tid = threadIdx.x;
    int v = (tid < SCAN_NB) ? bsum[tid] : 0;
    s[tid] = v;
    __syncthreads();
    for (int off = 1; off < 512; off <<= 1) {
        int t = (tid >= off) ? s[tid - off] : 0;
        __syncthreads();
        s[tid] += t;
        __syncthreads();
    }
    if (tid < SCAN_NB) bsum[tid] = s[tid] - v;
}

__global__ __launch_bounds__(256) void scan_final(const int* __restrict__ cnt, const int* __restrict__ bsum,
                                                  int* __restrict__ rp, int* __restrict__ cur) {
    __shared__ int s[256];
    int i = blockIdx.x * 256 + threadIdx.x;
    int v = (i < NN) ? cnt[i] : 0;
    s[threadIdx.x] = v;
    __syncthreads();
    for (int off = 1; off < 256; off <<= 1) {
        int t = (threadIdx.x >= off) ? s[threadIdx.x - off] : 0;
        __syncthreads();
        s[threadIdx.x] += t;
        __syncthreads();
    }
    int excl = s[threadIdx.x] - v + bsum[blockIdx.x];
    if (i < NN) { rp[i] = excl; cur[i] = excl; }
    if (i == NN - 1) rp[NN] = excl + v;
}

__global__ __launch_bounds__(256) void scatter_k(const int* __restrict__ esrc, const int* __restrict__ edst,
                                                 const float* __restrict__ av, int* __restrict__ cur,
                                                 int2* __restrict__ rec) {
    int e = blockIdx.x * 256 + threadIdx.x;
    if (e < NE) {
        int d = edst[e];
        int p = atomicAdd(&cur[d], 1);
        rec[p] = make_int2(esrc[e], __float_as_int(av[e]));
    }
}

// ---------------- GEMM: S = X @ W  (f16 in, f16 out, f32 acc, MFMA) ----------------
// per block: 64 rows, 4 waves x 16 rows; wave covers 16x128 output.
// A frag: lane holds X[row0 + (l&15)][32s + (l>>4)*8 .. +8]
// B frag: lane holds W[32s + (l>>4)*8 .. +8][16t + (l&15)]  (from Wt[n][k])
// D: col = 16t + (l&15), row = row0 + (l>>4)*4 + j

__global__ __launch_bounds__(256) void gemm_mfma(const _Float16* __restrict__ X, const _Float16* __restrict__ Wt,
                                                 _Float16* __restrict__ S) {
    const int wid = threadIdx.x >> 6;
    const int lane = threadIdx.x & 63;
    const int r = lane & 15, kb = lane >> 4;
    const int row0 = blockIdx.x * 64 + wid * 16;
    int arow = row0 + r;
    if (arow >= NN) arow = NN - 1;          // clamp; stores predicated below
    const _Float16* xp = X + (size_t)arow * NH + kb * 8;
    half8 a0 = *(const half8*)(xp);
    half8 a1 = *(const half8*)(xp + 32);
    half8 a2 = *(const half8*)(xp + 64);
    half8 a3 = *(const half8*)(xp + 96);
    f32x4 acc[8];
#pragma unroll
    for (int t = 0; t < 8; t++) acc[t] = (f32x4){0.f, 0.f, 0.f, 0.f};
#pragma unroll
    for (int t = 0; t < 8; t++) {
        const _Float16* wp = Wt + (size_t)(16 * t + r) * NH + kb * 8;
        half8 b0 = *(const half8*)(wp);
        half8 b1 = *(const half8*)(wp + 32);
        half8 b2 = *(const half8*)(wp + 64);
        half8 b3 = *(const half8*)(wp + 96);
        acc[t] = __builtin_amdgcn_mfma_f32_16x16x32_f16(a0, b0, acc[t], 0, 0, 0);
        acc[t] = __builtin_amdgcn_mfma_f32_16x16x32_f16(a1, b1, acc[t], 0, 0, 0);
        acc[t] = __builtin_amdgcn_mfma_f32_16x16x32_f16(a2, b2, acc[t], 0, 0, 0);
        acc[t] = __builtin_amdgcn_mfma_f32_16x16x32_f16(a3, b3, acc[t], 0, 0, 0);
    }
    const int orow = row0 + kb * 4;
#pragma unroll
    for (int j = 0; j < 4; j++) {
        if (orow + j < NN) {
            _Float16* sp = S + (size_t)(orow + j) * NH + r;
#pragma unroll
            for (int t = 0; t < 8; t++) sp[16 * t] = (_Float16)acc[t][j];
        }
    }
}

// ---------------- SPMM (CSR) + bias + relu, f16 rows, 4-edge ILP ----------------

__global__ __launch_bounds__(256) void spmm_f16(const _Float16* __restrict__ S, const int2* __restrict__ rec,
                                                const int* __restrict__ rp, const float* __restrict__ bias,
                                                _Float16* __restrict__ Xo) {
    int node = blockIdx.x * 4 + (threadIdx.x >> 6);
    if (node >= NN) return;
    int lane = threadIdx.x & 63;
    int g = lane >> 4;        // edge group 0..3
    int c = lane & 15;        // cols 8c..8c+7
    int beg = rp[node], end = rp[node + 1];
    float acc[8] = {0.f, 0.f, 0.f, 0.f, 0.f, 0.f, 0.f, 0.f};
    for (int e = beg + g; e < end; e += 4) {
        int2 rv = rec[e];
        float v = __int_as_float(rv.y);
        half8 srow = *(const half8*)&S[(size_t)rv.x * NH + c * 8];
#pragma unroll
        for (int j = 0; j < 8; j++) acc[j] = fmaf(v, (float)srow[j], acc[j]);
    }
#pragma unroll
    for (int j = 0; j < 8; j++) {
        acc[j] += __shfl_xor(acc[j], 16, 64);
        acc[j] += __shfl_xor(acc[j], 32, 64);
    }
    if (g == 0) {
        float4 b0 = *(const float4*)&bias[c * 8];
        float4 b1 = *(const float4*)&bias[c * 8 + 4];
        half8 o;
        o[0] = (_Float16)fmaxf(acc[0] + b0.x, 0.f);
        o[1] = (_Float16)fmaxf(acc[1] + b0.y, 0.f);
        o[2] = (_Float16)fmaxf(acc[2] + b0.z, 0.f);
        o[3] = (_Float16)fmaxf(acc[3] + b0.w, 0.f);
        o[4] = (_Float16)fmaxf(acc[4] + b1.x, 0.f);
        o[5] = (_Float16)fmaxf(acc[5] + b1.y, 0.f);
        o[6] = (_Float16)fmaxf(acc[6] + b1.z, 0.f);
        o[7] = (_Float16)fmaxf(acc[7] + b1.w, 0.f);
        *(half8*)&Xo[(size_t)node * NH + c * 8] = o;
    }
}

// ---------------- layer 10 ----------------

__global__ __launch_bounds__(256) void dot128_f16(const _Float16* __restrict__ X, const float* __restrict__ w,
                                                  float* __restrict__ s10) {
    int node = blockIdx.x * 4 + (threadIdx.x >> 6);
    if (node >= NN) return;
    int lane = threadIdx.x & 63;
    half2v xv = *(const half2v*)&X[(size_t)node * NH + lane * 2];
    float2 wv = *(const float2*)&w[lane * 2];
    float p = (float)xv[0] * wv.x + (float)xv[1] * wv.y;
#pragma unroll
    for (int off = 32; off; off >>= 1) p += __shfl_down(p, off, 64);
    if (lane == 0) s10[node] = p;
}

__global__ __launch_bounds__(256) void spmm_scalar(const float* __restrict__ s10, const int2* __restrict__ rec,
                                                   const int* __restrict__ rp, const float* __restrict__ b10,
                                                   float* __restrict__ o10) {
    int node = blockIdx.x * 256 + threadIdx.x;
    if (node >= NN) return;
    int beg = rp[node], end = rp[node + 1];
    float a = 0.f;
    for (int e = beg; e < end; e++) {
        int2 r = rec[e];
        a = fmaf(__int_as_float(r.y), s10[r.x], a);
    }
    o10[node] = a + b10[0];
}

// ---------------- log_softmax ----------------

#define LSM_NB 240

__global__ __launch_bounds__(256) void lsm_max(const float* __restrict__ v, float* __restrict__ pmax) {
    __shared__ float s[256];
    float m = -FLT_MAX;
    for (int i = blockIdx.x * 256 + threadIdx.x; i < NN; i += LSM_NB * 256) m = fmaxf(m, v[i]);
    s[threadIdx.x] = m;
    __syncthreads();
    for (int off = 128; off; off >>= 1) {
        if (threadIdx.x < off) s[threadIdx.x] = fmaxf(s[threadIdx.x], s[threadIdx.x + off]);
        __syncthreads();
    }
    if (threadIdx.x == 0) pmax[blockIdx.x] = s[0];
}

__global__ __launch_bounds__(256) void lsm_sum(const float* __restrict__ v, const float* __restrict__ pmax,
                                               float* __restrict__ psum) {
    __shared__ float s[256];
    float m = -FLT_MAX;
    if (threadIdx.x < LSM_NB) m = pmax[threadIdx.x];
    s[threadIdx.x] = m;
    __syncthreads();
    for (int off = 128; off; off >>= 1) {
        if (threadIdx.x < off) s[threadIdx.x] = fmaxf(s[threadIdx.x], s[threadIdx.x + off]);
        __syncthreads();
    }
    float gm = s[0];
    __syncthreads();
    float sum = 0.f;
    for (int i = blockIdx.x * 256 + threadIdx.x; i < NN; i += LSM_NB * 256) sum += expf(v[i] - gm);
    s[threadIdx.x] = sum;
    __syncthreads();
    for (int off = 128; off; off >>= 1) {
        if (threadIdx.x < off) s[threadIdx.x] += s[threadIdx.x + off];
        __syncthreads();
    }
    if (threadIdx.x == 0) psum[blockIdx.x] = s[0];
}

__global__ __launch_bounds__(256) void lsm_fin(const float* __restrict__ pmax, const float* __restrict__ psum,
                                               float* __restrict__ c) {
    __shared__ float s[256];
    float m = -FLT_MAX, sum = 0.f;
    if (threadIdx.x < LSM_NB) { m = pmax[threadIdx.x]; sum = psum[threadIdx.x]; }
    s[threadIdx.x] = m;
    __syncthreads();
    for (int off = 128; off; off >>= 1) {
        if (threadIdx.x < off) s[threadIdx.x] = fmaxf(s[threadIdx.x], s[threadIdx.x + off]);
        __syncthreads();
    }
    float gm = s[0];
    __syncthreads();
    s[threadIdx.x] = sum;
    __syncthreads();
    for (int off = 128; off; off >>= 1) {
        if (threadIdx.x < off) s[threadIdx.x] += s[threadIdx.x + off];
        __syncthreads();
    }
    if (threadIdx.x == 0) c[0] = gm + logf(s[0]);
}

__global__ __launch_bounds__(256) void lsm_write(const float* __restrict__ o10, const float* __restrict__ c,
                                                 float* __restrict__ out) {
    int i = blockIdx.x * 256 + threadIdx.x;
    if (i < NN) out[i] = o10[i] - c[0];
}

// ---------------- launch ----------------

extern "C" void kernel_launch(void* const* d_in, const int* in_sizes, int n_in,
                              void* d_out, int out_size, void* d_ws, size_t ws_size,
                              hipStream_t stream) {
    const float* features = (const float*)d_in[0];
    const float* adj_vals = (const float*)d_in[1];
    const float* Ws       = (const float*)d_in[2];
    const float* bs       = (const float*)d_in[3];
    const float* W10      = (const float*)d_in[4];
    const float* b10      = (const float*)d_in[5];
    const int*   esrc     = (const int*)d_in[6];
    const int*   edst     = (const int*)d_in[7];
    float* out = (float*)d_out;

    char* ws = (char*)d_ws;
    const size_t SZH = (size_t)NN * NH * 2;          // 25.6 MB per f16 buffer
    _Float16* S_h = (_Float16*)(ws);
    _Float16* xA  = (_Float16*)(ws + SZH);
    _Float16* xB  = (_Float16*)(ws + 2 * SZH);       // also holds f16 features
    _Float16* Wt  = (_Float16*)(ws + 3 * SZH);       // 9*128*128 f16
    char* p = ws + 3 * SZH + (size_t)N_MID * NH * NH * 2;
    int2* rec = (int2*)p;                            // 12.8 MB
    int* cnt  = (int*)(p + (size_t)NE * 8);
    int* rp   = cnt + NN;
    int* cur  = rp + NN + 1;
    int* bsum = cur + NN;
    float* s10 = (float*)(bsum + SCAN_NB);
    float* o10 = s10 + NN;
    float* pmax = o10 + NN;
    float* psum = pmax + LSM_NB;
    float* cbuf = psum + LSM_NB;

    // prep: dtype conversions
    conv_x<<<(NN * NH / 8 + 255) / 256, 256, 0, stream>>>(features, xB);
    conv_w<<<(N_MID * NH * NH + 255) / 256, 256, 0, stream>>>(Ws, Wt);

    // CSR build
    hipMemsetAsync(cnt, 0, (size_t)NN * 4, stream);
    count_k<<<(NE + 255) / 256, 256, 0, stream>>>(edst, cnt);
    scan_part<<<SCAN_NB, 256, 0, stream>>>(cnt, bsum);
    scan_top<<<1, 512, 0, stream>>>(bsum);
    scan_final<<<SCAN_NB, 256, 0, stream>>>(cnt, bsum, rp, cur);
    scatter_k<<<(NE + 255) / 256, 256, 0, stream>>>(esrc, edst, adj_vals, cur, rec);

    const _Float16* xin = xB;
    _Float16* xout = xA;
    for (int l = 0; l < N_MID; l++) {
        gemm_mfma<<<(NN + 63) / 64, 256, 0, stream>>>(xin, Wt + (size_t)l * NH * NH, S_h);
        spmm_f16<<<NN / 4, 256, 0, stream>>>(S_h, rec, rp, bs + (size_t)l * NH, xout);
        xin = xout;
        xout = (xout == xA) ? xB : xA;
    }

    dot128_f16<<<NN / 4, 256, 0, stream>>>(xin, W10, s10);
    spmm_scalar<<<(NN + 255) / 256, 256, 0, stream>>>(s10, rec, rp, b10, o10);
    lsm_max<<<LSM_NB, 256, 0, stream>>>(o10, pmax);
    lsm_sum<<<LSM_NB, 256, 0, stream>>>(o10, pmax, psum);
    lsm_fin<<<1, 256, 0, stream>>>(pmax, psum, cbuf);
    lsm_write<<<(NN + 255) / 256, 256, 0, stream>>>(o10, cbuf, out);
}

// Round 4
// 1023.387 us; speedup vs baseline: 2.6231x; 1.1359x over previous
//
#include <hip/hip_runtime.h>
#include <float.h>

#define NN 100000
#define NE 1600000
#define NH 128
#define N_MID 9
#define SCAN_NB ((NN + 255) / 256)   // 391
#define NBKT ((NN + 255) / 256)      // 391 dst-buckets of 256 nodes
#define P1_EPB 4096                  // edges per pass-1 block
#define P2_CAP 5120                  // LDS record capacity in pass 2 (avg 4096, sigma 64)

typedef _Float16 half8 __attribute__((ext_vector_type(8)));
typedef _Float16 half2v __attribute__((ext_vector_type(2)));
typedef float f32x4 __attribute__((ext_vector_type(4)));

// ---------------- dtype prep ----------------

__global__ __launch_bounds__(256) void conv_x(const float* __restrict__ in, _Float16* __restrict__ out) {
    int i = blockIdx.x * 256 + threadIdx.x;
    if (i >= NN * NH / 8) return;
    float4 v0 = ((const float4*)in)[i * 2];
    float4 v1 = ((const float4*)in)[i * 2 + 1];
    half8 o;
    o[0] = (_Float16)v0.x; o[1] = (_Float16)v0.y; o[2] = (_Float16)v0.z; o[3] = (_Float16)v0.w;
    o[4] = (_Float16)v1.x; o[5] = (_Float16)v1.y; o[6] = (_Float16)v1.z; o[7] = (_Float16)v1.w;
    ((half8*)out)[i] = o;
}

__global__ __launch_bounds__(256) void conv_w(const float* __restrict__ W, _Float16* __restrict__ Wt) {
    int i = blockIdx.x * 256 + threadIdx.x;
    if (i >= N_MID * NH * NH) return;
    int l = i / (NH * NH), rem = i % (NH * NH);
    int n = rem / NH, k = rem % NH;
    Wt[i] = (_Float16)W[l * NH * NH + k * NH + n];
}

// ---------------- CSR build: count + scan ----------------

__global__ __launch_bounds__(256) void count_k(const int* __restrict__ edst, int* __restrict__ cnt) {
    int e = blockIdx.x * 256 + threadIdx.x;
    if (e < NE) atomicAdd(&cnt[edst[e]], 1);
}

__global__ __launch_bounds__(256) void scan_part(const int* __restrict__ cnt, int* __restrict__ bsum) {
    __shared__ int s[256];
    int i = blockIdx.x * 256 + threadIdx.x;
    int v = (i < NN) ? cnt[i] : 0;
    s[threadIdx.x] = v;
    __syncthreads();
    for (int off = 128; off; off >>= 1) {
        if (threadIdx.x < off) s[threadIdx.x] += s[threadIdx.x + off];
        __syncthreads();
    }
    if (threadIdx.x == 0) bsum[blockIdx.x] = s[0];
}

__global__ __launch_bounds__(512) void scan_top(int* __restrict__ bsum) {
    __shared__ int s[512];
    int tid = threadIdx.x;
    int v = (tid < SCAN_NB) ? bsum[tid] : 0;
    s[tid] = v;
    __syncthreads();
    for (int off = 1; off < 512; off <<= 1) {
        int t = (tid >= off) ? s[tid - off] : 0;
        __syncthreads();
        s[tid] += t;
        __syncthreads();
    }
    if (tid < SCAN_NB) bsum[tid] = s[tid] - v;
}

__global__ __launch_bounds__(256) void scan_final(const int* __restrict__ cnt, const int* __restrict__ bsum,
                                                  int* __restrict__ rp, int* __restrict__ cur) {
    __shared__ int s[256];
    int i = blockIdx.x * 256 + threadIdx.x;
    int v = (i < NN) ? cnt[i] : 0;
    s[threadIdx.x] = v;
    __syncthreads();
    for (int off = 1; off < 256; off <<= 1) {
        int t = (threadIdx.x >= off) ? s[threadIdx.x - off] : 0;
        __syncthreads();
        s[threadIdx.x] += t;
        __syncthreads();
    }
    int excl = s[threadIdx.x] - v + bsum[blockIdx.x];
    if (i < NN) { rp[i] = excl; cur[i] = excl; }
    if (i == NN - 1) rp[NN] = excl + v;
}

// ---------------- edge sort: bucket pass + per-bucket counting sort ----------------

__global__ __launch_bounds__(256) void init_bkt(const int* __restrict__ rp, int* __restrict__ cur_b) {
    int b = blockIdx.x * 256 + threadIdx.x;
    if (b < NBKT) {
        int n0 = b * 256;
        cur_b[b] = rp[n0 > NN ? NN : n0];
    }
}

// pass 1: bin edges by dst>>8 into gbuf; record = (src | dlocal<<24, valbits)
__global__ __launch_bounds__(256) void p1_bucket(const int* __restrict__ esrc, const int* __restrict__ edst,
                                                 const float* __restrict__ av, int* __restrict__ cur_b,
                                                 int2* __restrict__ gbuf) {
    __shared__ int hist[NBKT];
    __shared__ int base[NBKT];
    __shared__ int rnk[NBKT];
    const int tid = threadIdx.x;
    for (int i = tid; i < NBKT; i += 256) { hist[i] = 0; rnk[i] = 0; }
    __syncthreads();
    const int e0 = blockIdx.x * P1_EPB;
    const int e1 = min(e0 + P1_EPB, NE);
    for (int e = e0 + tid; e < e1; e += 256) atomicAdd(&hist[edst[e] >> 8], 1);
    __syncthreads();
    for (int i = tid; i < NBKT; i += 256) {
        int h = hist[i];
        base[i] = h ? atomicAdd(&cur_b[i], h) : 0;
    }
    __syncthreads();
    for (int e = e0 + tid; e < e1; e += 256) {
        int d = edst[e];
        int b = d >> 8;
        int r = atomicAdd(&rnk[b], 1);
        gbuf[base[b] + r] = make_int2(esrc[e] | ((d & 255) << 24), __float_as_int(av[e]));
    }
}

// pass 2: one block per bucket; LDS counting sort by dlocal, coalesced write to rec
__global__ __launch_bounds__(256) void p2_sort(const int2* __restrict__ gbuf, const int* __restrict__ rp,
                                               int* __restrict__ cur, int2* __restrict__ rec) {
    __shared__ int hist[256];
    __shared__ int sc[256];
    __shared__ int offs[256];
    __shared__ int r2[256];
    __shared__ int2 buf[P2_CAP];
    const int b = blockIdx.x;
    const int tid = threadIdx.x;
    const int n0 = b * 256;
    const int n1 = min(n0 + 256, NN);
    const int e0 = rp[n0];
    const int e1 = rp[n1];
    const int n = e1 - e0;
    if (n > P2_CAP) {   // statistically unreachable fallback
        for (int i = tid; i < n; i += 256) {
            int2 rv = gbuf[e0 + i];
            int d = n0 + ((unsigned)rv.x >> 24);
            int p = atomicAdd(&cur[d], 1);
            rec[p] = make_int2(rv.x & 0x00FFFFFF, rv.y);
        }
        return;
    }
    hist[tid] = 0; r2[tid] = 0;
    __syncthreads();
    for (int i = tid; i < n; i += 256) atomicAdd(&hist[(unsigned)gbuf[e0 + i].x >> 24], 1);
    __syncthreads();
    sc[tid] = hist[tid];
    __syncthreads();
    for (int off = 1; off < 256; off <<= 1) {
        int t = (tid >= off) ? sc[tid - off] : 0;
        __syncthreads();
        sc[tid] += t;
        __syncthreads();
    }
    offs[tid] = sc[tid] - hist[tid];
    __syncthreads();
    for (int i = tid; i < n; i += 256) {
        int2 rv = gbuf[e0 + i];
        int dl = (unsigned)rv.x >> 24;
        int p = offs[dl] + atomicAdd(&r2[dl], 1);
        buf[p] = make_int2(rv.x & 0x00FFFFFF, rv.y);
    }
    __syncthreads();
    for (int i = tid; i < n; i += 256) rec[e0 + i] = buf[i];
}

// ---------------- GEMM: S = X @ W  (f16 in/out, f32 acc, MFMA) ----------------

__global__ __launch_bounds__(256) void gemm_mfma(const _Float16* __restrict__ X, const _Float16* __restrict__ Wt,
                                                 _Float16* __restrict__ S) {
    const int wid = threadIdx.x >> 6;
    const int lane = threadIdx.x & 63;
    const int r = lane & 15, kb = lane >> 4;
    const int row0 = blockIdx.x * 64 + wid * 16;
    int arow = row0 + r;
    if (arow >= NN) arow = NN - 1;
    const _Float16* xp = X + (size_t)arow * NH + kb * 8;
    half8 a0 = *(const half8*)(xp);
    half8 a1 = *(const half8*)(xp + 32);
    half8 a2 = *(const half8*)(xp + 64);
    half8 a3 = *(const half8*)(xp + 96);
    f32x4 acc[8];
#pragma unroll
    for (int t = 0; t < 8; t++) acc[t] = (f32x4){0.f, 0.f, 0.f, 0.f};
#pragma unroll
    for (int t = 0; t < 8; t++) {
        const _Float16* wp = Wt + (size_t)(16 * t + r) * NH + kb * 8;
        half8 b0 = *(const half8*)(wp);
        half8 b1 = *(const half8*)(wp + 32);
        half8 b2 = *(const half8*)(wp + 64);
        half8 b3 = *(const half8*)(wp + 96);
        acc[t] = __builtin_amdgcn_mfma_f32_16x16x32_f16(a0, b0, acc[t], 0, 0, 0);
        acc[t] = __builtin_amdgcn_mfma_f32_16x16x32_f16(a1, b1, acc[t], 0, 0, 0);
        acc[t] = __builtin_amdgcn_mfma_f32_16x16x32_f16(a2, b2, acc[t], 0, 0, 0);
        acc[t] = __builtin_amdgcn_mfma_f32_16x16x32_f16(a3, b3, acc[t], 0, 0, 0);
    }
    const int orow = row0 + kb * 4;
#pragma unroll
    for (int j = 0; j < 4; j++) {
        if (orow + j < NN) {
            _Float16* sp = S + (size_t)(orow + j) * NH + r;
#pragma unroll
            for (int t = 0; t < 8; t++) sp[16 * t] = (_Float16)acc[t][j];
        }
    }
}

// ---------------- SPMM (CSR) + bias + relu, f16 rows, 8-row MLP ----------------

__global__ __launch_bounds__(256) void spmm_f16(const _Float16* __restrict__ S, const int2* __restrict__ rec,
                                                const int* __restrict__ rp, const float* __restrict__ bias,
                                                _Float16* __restrict__ Xo) {
    int node = blockIdx.x * 4 + (threadIdx.x >> 6);
    if (node >= NN) return;
    int lane = threadIdx.x & 63;
    int g = lane >> 4;        // edge group 0..3
    int c = lane & 15;        // cols 8c..8c+7
    int beg = rp[node], end = rp[node + 1];
    float acc[8] = {0.f, 0.f, 0.f, 0.f, 0.f, 0.f, 0.f, 0.f};
    float acc2[8] = {0.f, 0.f, 0.f, 0.f, 0.f, 0.f, 0.f, 0.f};
    int e = beg + g;
    for (; e + 4 < end; e += 8) {
        int2 rv1 = rec[e];
        int2 rv2 = rec[e + 4];
        half8 r1 = *(const half8*)&S[(size_t)rv1.x * NH + c * 8];
        half8 r2 = *(const half8*)&S[(size_t)rv2.x * NH + c * 8];
        float v1 = __int_as_float(rv1.y);
        float v2 = __int_as_float(rv2.y);
#pragma unroll
        for (int j = 0; j < 8; j++) {
            acc[j]  = fmaf(v1, (float)r1[j], acc[j]);
            acc2[j] = fmaf(v2, (float)r2[j], acc2[j]);
        }
    }
    if (e < end) {
        int2 rv = rec[e];
        float v = __int_as_float(rv.y);
        half8 r1 = *(const half8*)&S[(size_t)rv.x * NH + c * 8];
#pragma unroll
        for (int j = 0; j < 8; j++) acc[j] = fmaf(v, (float)r1[j], acc[j]);
    }
#pragma unroll
    for (int j = 0; j < 8; j++) {
        acc[j] += acc2[j];
        acc[j] += __shfl_xor(acc[j], 16, 64);
        acc[j] += __shfl_xor(acc[j], 32, 64);
    }
    if (g == 0) {
        float4 b0 = *(const float4*)&bias[c * 8];
        float4 b1 = *(const float4*)&bias[c * 8 + 4];
        half8 o;
        o[0] = (_Float16)fmaxf(acc[0] + b0.x, 0.f);
        o[1] = (_Float16)fmaxf(acc[1] + b0.y, 0.f);
        o[2] = (_Float16)fmaxf(acc[2] + b0.z, 0.f);
        o[3] = (_Float16)fmaxf(acc[3] + b0.w, 0.f);
        o[4] = (_Float16)fmaxf(acc[4] + b1.x, 0.f);
        o[5] = (_Float16)fmaxf(acc[5] + b1.y, 0.f);
        o[6] = (_Float16)fmaxf(acc[6] + b1.z, 0.f);
        o[7] = (_Float16)fmaxf(acc[7] + b1.w, 0.f);
        *(half8*)&Xo[(size_t)node * NH + c * 8] = o;
    }
}

// ---------------- layer 10 ----------------

__global__ __launch_bounds__(256) void dot128_f16(const _Float16* __restrict__ X, const float* __restrict__ w,
                                                  float* __restrict__ s10) {
    int node = blockIdx.x * 4 + (threadIdx.x >> 6);
    if (node >= NN) return;
    int lane = threadIdx.x & 63;
    half2v xv = *(const half2v*)&X[(size_t)node * NH + lane * 2];
    float2 wv = *(const float2*)&w[lane * 2];
    float p = (float)xv[0] * wv.x + (float)xv[1] * wv.y;
#pragma unroll
    for (int off = 32; off; off >>= 1) p += __shfl_down(p, off, 64);
    if (lane == 0) s10[node] = p;
}

__global__ __launch_bounds__(256) void spmm_scalar(const float* __restrict__ s10, const int2* __restrict__ rec,
                                                   const int* __restrict__ rp, const float* __restrict__ b10,
                                                   float* __restrict__ o10) {
    int node = blockIdx.x * 256 + threadIdx.x;
    if (node >= NN) return;
    int beg = rp[node], end = rp[node + 1];
    float a = 0.f;
    for (int e = beg; e < end; e++) {
        int2 r = rec[e];
        a = fmaf(__int_as_float(r.y), s10[r.x], a);
    }
    o10[node] = a + b10[0];
}

// ---------------- log_softmax ----------------

#define LSM_NB 240

__global__ __launch_bounds__(256) void lsm_max(const float* __restrict__ v, float* __restrict__ pmax) {
    __shared__ float s[256];
    float m = -FLT_MAX;
    for (int i = blockIdx.x * 256 + threadIdx.x; i < NN; i += LSM_NB * 256) m = fmaxf(m, v[i]);
    s[threadIdx.x] = m;
    __syncthreads();
    for (int off = 128; off; off >>= 1) {
        if (threadIdx.x < off) s[threadIdx.x] = fmaxf(s[threadIdx.x], s[threadIdx.x + off]);
        __syncthreads();
    }
    if (threadIdx.x == 0) pmax[blockIdx.x] = s[0];
}

__global__ __launch_bounds__(256) void lsm_sum(const float* __restrict__ v, const float* __restrict__ pmax,
                                               float* __restrict__ psum) {
    __shared__ float s[256];
    float m = -FLT_MAX;
    if (threadIdx.x < LSM_NB) m = pmax[threadIdx.x];
    s[threadIdx.x] = m;
    __syncthreads();
    for (int off = 128; off; off >>= 1) {
        if (threadIdx.x < off) s[threadIdx.x] = fmaxf(s[threadIdx.x], s[threadIdx.x + off]);
        __syncthreads();
    }
    float gm = s[0];
    __syncthreads();
    float sum = 0.f;
    for (int i = blockIdx.x * 256 + threadIdx.x; i < NN; i += LSM_NB * 256) sum += expf(v[i] - gm);
    s[threadIdx.x] = sum;
    __syncthreads();
    for (int off = 128; off; off >>= 1) {
        if (threadIdx.x < off) s[threadIdx.x] += s[threadIdx.x + off];
        __syncthreads();
    }
    if (threadIdx.x == 0) psum[blockIdx.x] = s[0];
}

__global__ __launch_bounds__(256) void lsm_fin(const float* __restrict__ pmax, const float* __restrict__ psum,
                                               float* __restrict__ c) {
    __shared__ float s[256];
    float m = -FLT_MAX, sum = 0.f;
    if (threadIdx.x < LSM_NB) { m = pmax[threadIdx.x]; sum = psum[threadIdx.x]; }
    s[threadIdx.x] = m;
    __syncthreads();
    for (int off = 128; off; off >>= 1) {
        if (threadIdx.x < off) s[threadIdx.x] = fmaxf(s[threadIdx.x], s[threadIdx.x + off]);
        __syncthreads();
    }
    float gm = s[0];
    __syncthreads();
    s[threadIdx.x] = sum;
    __syncthreads();
    for (int off = 128; off; off >>= 1) {
        if (threadIdx.x < off) s[threadIdx.x] += s[threadIdx.x + off];
        __syncthreads();
    }
    if (threadIdx.x == 0) c[0] = gm + logf(s[0]);
}

__global__ __launch_bounds__(256) void lsm_write(const float* __restrict__ o10, const float* __restrict__ c,
                                                 float* __restrict__ out) {
    int i = blockIdx.x * 256 + threadIdx.x;
    if (i < NN) out[i] = o10[i] - c[0];
}

// ---------------- launch ----------------

extern "C" void kernel_launch(void* const* d_in, const int* in_sizes, int n_in,
                              void* d_out, int out_size, void* d_ws, size_t ws_size,
                              hipStream_t stream) {
    const float* features = (const float*)d_in[0];
    const float* adj_vals = (const float*)d_in[1];
    const float* Ws       = (const float*)d_in[2];
    const float* bs       = (const float*)d_in[3];
    const float* W10      = (const float*)d_in[4];
    const float* b10      = (const float*)d_in[5];
    const int*   esrc     = (const int*)d_in[6];
    const int*   edst     = (const int*)d_in[7];
    float* out = (float*)d_out;

    char* ws = (char*)d_ws;
    const size_t SZH = (size_t)NN * NH * 2;          // 25.6 MB per f16 buffer
    _Float16* S_h = (_Float16*)(ws);
    _Float16* xA  = (_Float16*)(ws + SZH);
    _Float16* xB  = (_Float16*)(ws + 2 * SZH);       // f16 features live here first
    _Float16* Wt  = (_Float16*)(ws + 3 * SZH);
    char* p = ws + 3 * SZH + (size_t)N_MID * NH * NH * 2;
    int2* rec  = (int2*)p;                           // 12.8 MB
    int2* gbuf = (int2*)(p + (size_t)NE * 8);        // 12.8 MB
    int* cnt   = (int*)(p + 2 * (size_t)NE * 8);
    int* rp    = cnt + NN;
    int* cur   = rp + NN + 1;
    int* bsum  = cur + NN;
    int* cur_b = bsum + SCAN_NB;
    float* s10 = (float*)(cur_b + NBKT);
    float* o10 = s10 + NN;
    float* pmax = o10 + NN;
    float* psum = pmax + LSM_NB;
    float* cbuf = psum + LSM_NB;

    // prep: dtype conversions
    conv_x<<<(NN * NH / 8 + 255) / 256, 256, 0, stream>>>(features, xB);
    conv_w<<<(N_MID * NH * NH + 255) / 256, 256, 0, stream>>>(Ws, Wt);

    // CSR build
    hipMemsetAsync(cnt, 0, (size_t)NN * 4, stream);
    count_k<<<(NE + 255) / 256, 256, 0, stream>>>(edst, cnt);
    scan_part<<<SCAN_NB, 256, 0, stream>>>(cnt, bsum);
    scan_top<<<1, 512, 0, stream>>>(bsum);
    scan_final<<<SCAN_NB, 256, 0, stream>>>(cnt, bsum, rp, cur);
    init_bkt<<<(NBKT + 255) / 256, 256, 0, stream>>>(rp, cur_b);
    p1_bucket<<<(NE + P1_EPB - 1) / P1_EPB, 256, 0, stream>>>(esrc, edst, adj_vals, cur_b, gbuf);
    p2_sort<<<NBKT, 256, 0, stream>>>(gbuf, rp, cur, rec);

    const _Float16* xin = xB;
    _Float16* xout = xA;
    for (int l = 0; l < N_MID; l++) {
        gemm_mfma<<<(NN + 63) / 64, 256, 0, stream>>>(xin, Wt + (size_t)l * NH * NH, S_h);
        spmm_f16<<<NN / 4, 256, 0, stream>>>(S_h, rec, rp, bs + (size_t)l * NH, xout);
        xin = xout;
        xout = (xout == xA) ? xB : xA;
    }

    dot128_f16<<<NN / 4, 256, 0, stream>>>(xin, W10, s10);
    spmm_scalar<<<(NN + 255) / 256, 256, 0, stream>>>(s10, rec, rp, b10, o10);
    lsm_max<<<LSM_NB, 256, 0, stream>>>(o10, pmax);
    lsm_sum<<<LSM_NB, 256, 0, stream>>>(o10, pmax, psum);
    lsm_fin<<<1, 256, 0, stream>>>(pmax, psum, cbuf);
    lsm_write<<<(NN + 255) / 256, 256, 0, stream>>>(o10, cbuf, out);
}

// Round 5
// 945.619 us; speedup vs baseline: 2.8388x; 1.0822x over previous
//
#include <hip/hip_runtime.h>
#include <float.h>

#define NN 100000
#define NE 1600000
#define NH 128
#define N_MID 9
#define NBKT ((NN + 255) / 256)      // 391 dst-buckets of 256 nodes
#define P1_EPB 4096                  // edges per pass-1 block
#define NP1B ((NE + P1_EPB - 1) / P1_EPB)  // 391 pass-1 blocks
#define P2_CAP 5120                  // LDS record capacity in pass 2 (avg 4092, sigma 64)

typedef _Float16 half8 __attribute__((ext_vector_type(8)));
typedef _Float16 half2v __attribute__((ext_vector_type(2)));
typedef float f32x4 __attribute__((ext_vector_type(4)));

// ---------------- dtype prep ----------------

__global__ __launch_bounds__(256) void conv_x(const float* __restrict__ in, _Float16* __restrict__ out) {
    int i = blockIdx.x * 256 + threadIdx.x;
    if (i >= NN * NH / 8) return;
    float4 v0 = ((const float4*)in)[i * 2];
    float4 v1 = ((const float4*)in)[i * 2 + 1];
    half8 o;
    o[0] = (_Float16)v0.x; o[1] = (_Float16)v0.y; o[2] = (_Float16)v0.z; o[3] = (_Float16)v0.w;
    o[4] = (_Float16)v1.x; o[5] = (_Float16)v1.y; o[6] = (_Float16)v1.z; o[7] = (_Float16)v1.w;
    ((half8*)out)[i] = o;
}

__global__ __launch_bounds__(256) void conv_w(const float* __restrict__ W, _Float16* __restrict__ Wt) {
    int i = blockIdx.x * 256 + threadIdx.x;
    if (i >= N_MID * NH * NH) return;
    int l = i / (NH * NH), rem = i % (NH * NH);
    int n = rem / NH, k = rem % NH;
    Wt[i] = (_Float16)W[l * NH * NH + k * NH + n];
}

// ---------------- edge sort: atomic-free bucket pipeline ----------------

// per-block LDS histogram of dst>>8, coalesced write to bh[block][NBKT]
__global__ __launch_bounds__(256) void bhist_k(const int* __restrict__ edst, int* __restrict__ bh) {
    __shared__ int hist[NBKT];
    const int tid = threadIdx.x;
    for (int i = tid; i < NBKT; i += 256) hist[i] = 0;
    __syncthreads();
    const int e0 = blockIdx.x * P1_EPB;
    const int e1 = min(e0 + P1_EPB, NE);
    for (int e = e0 + tid; e < e1; e += 256) atomicAdd(&hist[edst[e] >> 8], 1);
    __syncthreads();
    for (int i = tid; i < NBKT; i += 256) bh[blockIdx.x * NBKT + i] = hist[i];
}

// per bucket b: exclusive scan over blocks -> obh[blk][b], total -> btot[b]
__global__ __launch_bounds__(512) void bscan_cols(const int* __restrict__ bh, int* __restrict__ obh,
                                                  int* __restrict__ btot) {
    __shared__ int s[512];
    const int b = blockIdx.x, tid = threadIdx.x;
    int v = (tid < NP1B) ? bh[tid * NBKT + b] : 0;
    s[tid] = v;
    __syncthreads();
    for (int off = 1; off < 512; off <<= 1) {
        int t = (tid >= off) ? s[tid - off] : 0;
        __syncthreads();
        s[tid] += t;
        __syncthreads();
    }
    if (tid < NP1B) obh[tid * NBKT + b] = s[tid] - v;
    if (tid == NP1B - 1) btot[b] = s[tid];
}

// exclusive scan of bucket totals -> bbase[0..NBKT]
__global__ __launch_bounds__(512) void bscan_top(const int* __restrict__ btot, int* __restrict__ bbase) {
    __shared__ int s[512];
    const int tid = threadIdx.x;
    int v = (tid < NBKT) ? btot[tid] : 0;
    s[tid] = v;
    __syncthreads();
    for (int off = 1; off < 512; off <<= 1) {
        int t = (tid >= off) ? s[tid - off] : 0;
        __syncthreads();
        s[tid] += t;
        __syncthreads();
    }
    if (tid < NBKT) bbase[tid] = s[tid] - v;
    if (tid == NBKT - 1) bbase[NBKT] = s[tid];   // == NE
}

// pass 1: bin edges into bucket-contiguous gbuf; record = (src | dlocal<<24, valbits)
__global__ __launch_bounds__(256) void p1_bucket(const int* __restrict__ esrc, const int* __restrict__ edst,
                                                 const float* __restrict__ av, const int* __restrict__ bbase,
                                                 const int* __restrict__ obh, int2* __restrict__ gbuf) {
    __shared__ int base[NBKT];
    __shared__ int rnk[NBKT];
    const int tid = threadIdx.x;
    for (int i = tid; i < NBKT; i += 256) {
        base[i] = bbase[i] + obh[blockIdx.x * NBKT + i];
        rnk[i] = 0;
    }
    __syncthreads();
    const int e0 = blockIdx.x * P1_EPB;
    const int e1 = min(e0 + P1_EPB, NE);
    for (int e = e0 + tid; e < e1; e += 256) {
        int d = edst[e];
        int b = d >> 8;
        int r = atomicAdd(&rnk[b], 1);
        gbuf[base[b] + r] = make_int2(esrc[e] | ((d & 255) << 24), __float_as_int(av[e]));
    }
}

// pass 2: one block per bucket; LDS counting sort by dlocal -> rec (coalesced) + rp
__global__ __launch_bounds__(256) void p2_sort(const int2* __restrict__ gbuf, const int* __restrict__ bbase,
                                               int* __restrict__ rp, int2* __restrict__ rec) {
    __shared__ int hist[256];
    __shared__ int sc[256];
    __shared__ int offs[256];
    __shared__ int r2[256];
    __shared__ int2 buf[P2_CAP];
    const int b = blockIdx.x;
    const int tid = threadIdx.x;
    const int n0 = b * 256;
    const int e0 = bbase[b];
    const int e1 = bbase[b + 1];
    const int n = e1 - e0;
    hist[tid] = 0; r2[tid] = 0;
    __syncthreads();
    for (int i = tid; i < n; i += 256) atomicAdd(&hist[(unsigned)gbuf[e0 + i].x >> 24], 1);
    __syncthreads();
    sc[tid] = hist[tid];
    __syncthreads();
    for (int off = 1; off < 256; off <<= 1) {
        int t = (tid >= off) ? sc[tid - off] : 0;
        __syncthreads();
        sc[tid] += t;
        __syncthreads();
    }
    offs[tid] = sc[tid] - hist[tid];
    __syncthreads();
    // rp as a byproduct of the counting sort
    if (n0 + tid < NN) rp[n0 + tid] = e0 + offs[tid];
    if (b == NBKT - 1 && tid == 0) rp[NN] = e1;
    if (n <= P2_CAP) {
        for (int i = tid; i < n; i += 256) {
            int2 rv = gbuf[e0 + i];
            int dl = (unsigned)rv.x >> 24;
            int p = offs[dl] + atomicAdd(&r2[dl], 1);
            buf[p] = make_int2(rv.x & 0x00FFFFFF, rv.y);
        }
        __syncthreads();
        for (int i = tid; i < n; i += 256) rec[e0 + i] = buf[i];
    } else {  // statistically unreachable (16 sigma); direct scattered write, no global cursor
        for (int i = tid; i < n; i += 256) {
            int2 rv = gbuf[e0 + i];
            int dl = (unsigned)rv.x >> 24;
            int p = offs[dl] + atomicAdd(&r2[dl], 1);
            rec[e0 + p] = make_int2(rv.x & 0x00FFFFFF, rv.y);
        }
    }
}

// ---------------- GEMM: S = X @ W  (f16 in/out, f32 acc, MFMA) ----------------

__global__ __launch_bounds__(256) void gemm_mfma(const _Float16* __restrict__ X, const _Float16* __restrict__ Wt,
                                                 _Float16* __restrict__ S) {
    const int wid = threadIdx.x >> 6;
    const int lane = threadIdx.x & 63;
    const int r = lane & 15, kb = lane >> 4;
    const int row0 = blockIdx.x * 64 + wid * 16;
    int arow = row0 + r;
    if (arow >= NN) arow = NN - 1;
    const _Float16* xp = X + (size_t)arow * NH + kb * 8;
    half8 a0 = *(const half8*)(xp);
    half8 a1 = *(const half8*)(xp + 32);
    half8 a2 = *(const half8*)(xp + 64);
    half8 a3 = *(const half8*)(xp + 96);
    f32x4 acc[8];
#pragma unroll
    for (int t = 0; t < 8; t++) acc[t] = (f32x4){0.f, 0.f, 0.f, 0.f};
#pragma unroll
    for (int t = 0; t < 8; t++) {
        const _Float16* wp = Wt + (size_t)(16 * t + r) * NH + kb * 8;
        half8 b0 = *(const half8*)(wp);
        half8 b1 = *(const half8*)(wp + 32);
        half8 b2 = *(const half8*)(wp + 64);
        half8 b3 = *(const half8*)(wp + 96);
        acc[t] = __builtin_amdgcn_mfma_f32_16x16x32_f16(a0, b0, acc[t], 0, 0, 0);
        acc[t] = __builtin_amdgcn_mfma_f32_16x16x32_f16(a1, b1, acc[t], 0, 0, 0);
        acc[t] = __builtin_amdgcn_mfma_f32_16x16x32_f16(a2, b2, acc[t], 0, 0, 0);
        acc[t] = __builtin_amdgcn_mfma_f32_16x16x32_f16(a3, b3, acc[t], 0, 0, 0);
    }
    const int orow = row0 + kb * 4;
#pragma unroll
    for (int j = 0; j < 4; j++) {
        if (orow + j < NN) {
            _Float16* sp = S + (size_t)(orow + j) * NH + r;
#pragma unroll
            for (int t = 0; t < 8; t++) sp[16 * t] = (_Float16)acc[t][j];
        }
    }
}

// ---------------- SPMM (CSR) + bias + relu, f16 rows, 8-row MLP ----------------

__global__ __launch_bounds__(256) void spmm_f16(const _Float16* __restrict__ S, const int2* __restrict__ rec,
                                                const int* __restrict__ rp, const float* __restrict__ bias,
                                                _Float16* __restrict__ Xo) {
    int node = blockIdx.x * 4 + (threadIdx.x >> 6);
    if (node >= NN) return;
    int lane = threadIdx.x & 63;
    int g = lane >> 4;        // edge group 0..3
    int c = lane & 15;        // cols 8c..8c+7
    int beg = rp[node], end = rp[node + 1];
    float acc[8] = {0.f, 0.f, 0.f, 0.f, 0.f, 0.f, 0.f, 0.f};
    float acc2[8] = {0.f, 0.f, 0.f, 0.f, 0.f, 0.f, 0.f, 0.f};
    int e = beg + g;
    for (; e + 4 < end; e += 8) {
        int2 rv1 = rec[e];
        int2 rv2 = rec[e + 4];
        half8 r1 = *(const half8*)&S[(size_t)rv1.x * NH + c * 8];
        half8 r2 = *(const half8*)&S[(size_t)rv2.x * NH + c * 8];
        float v1 = __int_as_float(rv1.y);
        float v2 = __int_as_float(rv2.y);
#pragma unroll
        for (int j = 0; j < 8; j++) {
            acc[j]  = fmaf(v1, (float)r1[j], acc[j]);
            acc2[j] = fmaf(v2, (float)r2[j], acc2[j]);
        }
    }
    if (e < end) {
        int2 rv = rec[e];
        float v = __int_as_float(rv.y);
        half8 r1 = *(const half8*)&S[(size_t)rv.x * NH + c * 8];
#pragma unroll
        for (int j = 0; j < 8; j++) acc[j] = fmaf(v, (float)r1[j], acc[j]);
    }
#pragma unroll
    for (int j = 0; j < 8; j++) {
        acc[j] += acc2[j];
        acc[j] += __shfl_xor(acc[j], 16, 64);
        acc[j] += __shfl_xor(acc[j], 32, 64);
    }
    if (g == 0) {
        float4 b0 = *(const float4*)&bias[c * 8];
        float4 b1 = *(const float4*)&bias[c * 8 + 4];
        half8 o;
        o[0] = (_Float16)fmaxf(acc[0] + b0.x, 0.f);
        o[1] = (_Float16)fmaxf(acc[1] + b0.y, 0.f);
        o[2] = (_Float16)fmaxf(acc[2] + b0.z, 0.f);
        o[3] = (_Float16)fmaxf(acc[3] + b0.w, 0.f);
        o[4] = (_Float16)fmaxf(acc[4] + b1.x, 0.f);
        o[5] = (_Float16)fmaxf(acc[5] + b1.y, 0.f);
        o[6] = (_Float16)fmaxf(acc[6] + b1.z, 0.f);
        o[7] = (_Float16)fmaxf(acc[7] + b1.w, 0.f);
        *(half8*)&Xo[(size_t)node * NH + c * 8] = o;
    }
}

// ---------------- layer 10 ----------------

__global__ __launch_bounds__(256) void dot128_f16(const _Float16* __restrict__ X, const float* __restrict__ w,
                                                  float* __restrict__ s10) {
    int node = blockIdx.x * 4 + (threadIdx.x >> 6);
    if (node >= NN) return;
    int lane = threadIdx.x & 63;
    half2v xv = *(const half2v*)&X[(size_t)node * NH + lane * 2];
    float2 wv = *(const float2*)&w[lane * 2];
    float p = (float)xv[0] * wv.x + (float)xv[1] * wv.y;
#pragma unroll
    for (int off = 32; off; off >>= 1) p += __shfl_down(p, off, 64);
    if (lane == 0) s10[node] = p;
}

__global__ __launch_bounds__(256) void spmm_scalar(const float* __restrict__ s10, const int2* __restrict__ rec,
                                                   const int* __restrict__ rp, const float* __restrict__ b10,
                                                   float* __restrict__ o10) {
    int node = blockIdx.x * 256 + threadIdx.x;
    if (node >= NN) return;
    int beg = rp[node], end = rp[node + 1];
    float a = 0.f;
    for (int e = beg; e < end; e++) {
        int2 r = rec[e];
        a = fmaf(__int_as_float(r.y), s10[r.x], a);
    }
    o10[node] = a + b10[0];
}

// ---------------- log_softmax ----------------

#define LSM_NB 240

__global__ __launch_bounds__(256) void lsm_max(const float* __restrict__ v, float* __restrict__ pmax) {
    __shared__ float s[256];
    float m = -FLT_MAX;
    for (int i = blockIdx.x * 256 + threadIdx.x; i < NN; i += LSM_NB * 256) m = fmaxf(m, v[i]);
    s[threadIdx.x] = m;
    __syncthreads();
    for (int off = 128; off; off >>= 1) {
        if (threadIdx.x < off) s[threadIdx.x] = fmaxf(s[threadIdx.x], s[threadIdx.x + off]);
        __syncthreads();
    }
    if (threadIdx.x == 0) pmax[blockIdx.x] = s[0];
}

__global__ __launch_bounds__(256) void lsm_sum(const float* __restrict__ v, const float* __restrict__ pmax,
                                               float* __restrict__ psum) {
    __shared__ float s[256];
    float m = -FLT_MAX;
    if (threadIdx.x < LSM_NB) m = pmax[threadIdx.x];
    s[threadIdx.x] = m;
    __syncthreads();
    for (int off = 128; off; off >>= 1) {
        if (threadIdx.x < off) s[threadIdx.x] = fmaxf(s[threadIdx.x], s[threadIdx.x + off]);
        __syncthreads();
    }
    float gm = s[0];
    __syncthreads();
    float sum = 0.f;
    for (int i = blockIdx.x * 256 + threadIdx.x; i < NN; i += LSM_NB * 256) sum += expf(v[i] - gm);
    s[threadIdx.x] = sum;
    __syncthreads();
    for (int off = 128; off; off >>= 1) {
        if (threadIdx.x < off) s[threadIdx.x] += s[threadIdx.x + off];
        __syncthreads();
    }
    if (threadIdx.x == 0) psum[blockIdx.x] = s[0];
}

__global__ __launch_bounds__(256) void lsm_fin(const float* __restrict__ pmax, const float* __restrict__ psum,
                                               float* __restrict__ c) {
    __shared__ float s[256];
    float m = -FLT_MAX, sum = 0.f;
    if (threadIdx.x < LSM_NB) { m = pmax[threadIdx.x]; sum = psum[threadIdx.x]; }
    s[threadIdx.x] = m;
    __syncthreads();
    for (int off = 128; off; off >>= 1) {
        if (threadIdx.x < off) s[threadIdx.x] = fmaxf(s[threadIdx.x], s[threadIdx.x + off]);
        __syncthreads();
    }
    float gm = s[0];
    __syncthreads();
    s[threadIdx.x] = sum;
    __syncthreads();
    for (int off = 128; off; off >>= 1) {
        if (threadIdx.x < off) s[threadIdx.x] += s[threadIdx.x + off];
        __syncthreads();
    }
    if (threadIdx.x == 0) c[0] = gm + logf(s[0]);
}

__global__ __launch_bounds__(256) void lsm_write(const float* __restrict__ o10, const float* __restrict__ c,
                                                 float* __restrict__ out) {
    int i = blockIdx.x * 256 + threadIdx.x;
    if (i < NN) out[i] = o10[i] - c[0];
}

// ---------------- launch ----------------

extern "C" void kernel_launch(void* const* d_in, const int* in_sizes, int n_in,
                              void* d_out, int out_size, void* d_ws, size_t ws_size,
                              hipStream_t stream) {
    const float* features = (const float*)d_in[0];
    const float* adj_vals = (const float*)d_in[1];
    const float* Ws       = (const float*)d_in[2];
    const float* bs       = (const float*)d_in[3];
    const float* W10      = (const float*)d_in[4];
    const float* b10      = (const float*)d_in[5];
    const int*   esrc     = (const int*)d_in[6];
    const int*   edst     = (const int*)d_in[7];
    float* out = (float*)d_out;

    char* ws = (char*)d_ws;
    const size_t SZH = (size_t)NN * NH * 2;          // 25.6 MB per f16 buffer
    _Float16* S_h = (_Float16*)(ws);
    _Float16* xA  = (_Float16*)(ws + SZH);
    _Float16* xB  = (_Float16*)(ws + 2 * SZH);       // f16 features live here first
    _Float16* Wt  = (_Float16*)(ws + 3 * SZH);
    char* p = ws + 3 * SZH + (size_t)N_MID * NH * NH * 2;
    int2* rec  = (int2*)p;                           // 12.8 MB
    int2* gbuf = (int2*)(p + (size_t)NE * 8);        // 12.8 MB
    int* bh    = (int*)(p + 2 * (size_t)NE * 8);     // NP1B*NBKT
    int* obh   = bh + NP1B * NBKT;                   // NP1B*NBKT
    int* btot  = obh + NP1B * NBKT;                  // NBKT
    int* bbase = btot + NBKT;                        // NBKT+1
    int* rp    = bbase + NBKT + 1;                   // NN+1
    float* s10 = (float*)(rp + NN + 1);
    float* o10 = s10 + NN;
    float* pmax = o10 + NN;
    float* psum = pmax + LSM_NB;
    float* cbuf = psum + LSM_NB;

    // prep: dtype conversions
    conv_x<<<(NN * NH / 8 + 255) / 256, 256, 0, stream>>>(features, xB);
    conv_w<<<(N_MID * NH * NH + 255) / 256, 256, 0, stream>>>(Ws, Wt);

    // edge sort + CSR build (atomic-free except LDS)
    bhist_k<<<NP1B, 256, 0, stream>>>(edst, bh);
    bscan_cols<<<NBKT, 512, 0, stream>>>(bh, obh, btot);
    bscan_top<<<1, 512, 0, stream>>>(btot, bbase);
    p1_bucket<<<NP1B, 256, 0, stream>>>(esrc, edst, adj_vals, bbase, obh, gbuf);
    p2_sort<<<NBKT, 256, 0, stream>>>(gbuf, bbase, rp, rec);

    const _Float16* xin = xB;
    _Float16* xout = xA;
    for (int l = 0; l < N_MID; l++) {
        gemm_mfma<<<(NN + 63) / 64, 256, 0, stream>>>(xin, Wt + (size_t)l * NH * NH, S_h);
        spmm_f16<<<NN / 4, 256, 0, stream>>>(S_h, rec, rp, bs + (size_t)l * NH, xout);
        xin = xout;
        xout = (xout == xA) ? xB : xA;
    }

    dot128_f16<<<NN / 4, 256, 0, stream>>>(xin, W10, s10);
    spmm_scalar<<<(NN + 255) / 256, 256, 0, stream>>>(s10, rec, rp, b10, o10);
    lsm_max<<<LSM_NB, 256, 0, stream>>>(o10, pmax);
    lsm_sum<<<LSM_NB, 256, 0, stream>>>(o10, pmax, psum);
    lsm_fin<<<1, 256, 0, stream>>>(pmax, psum, cbuf);
    lsm_write<<<(NN + 255) / 256, 256, 0, stream>>>(o10, cbuf, out);
}

// Round 7
// 893.626 us; speedup vs baseline: 3.0040x; 1.0582x over previous
//
#include <hip/hip_runtime.h>
#include <float.h>

#define NN 100000
#define NE 1600000
#define NH 128
#define N_MID 9
#define NBKT ((NN + 255) / 256)      // 391 dst-buckets of 256 nodes
#define P1_EPB 4096                  // edges per pass-1 block
#define NP1B ((NE + P1_EPB - 1) / P1_EPB)  // 391 pass-1 blocks
#define P2_CAP 5120                  // LDS record capacity in pass 2 (avg 4092, sigma 64)

typedef _Float16 half8 __attribute__((ext_vector_type(8)));
typedef _Float16 half2v __attribute__((ext_vector_type(2)));
typedef float f32x4 __attribute__((ext_vector_type(4)));

// ---------------- dtype prep ----------------

__global__ __launch_bounds__(256) void conv_x(const float* __restrict__ in, _Float16* __restrict__ out) {
    int i = blockIdx.x * 256 + threadIdx.x;
    if (i >= NN * NH / 8) return;
    float4 v0 = ((const float4*)in)[i * 2];
    float4 v1 = ((const float4*)in)[i * 2 + 1];
    half8 o;
    o[0] = (_Float16)v0.x; o[1] = (_Float16)v0.y; o[2] = (_Float16)v0.z; o[3] = (_Float16)v0.w;
    o[4] = (_Float16)v1.x; o[5] = (_Float16)v1.y; o[6] = (_Float16)v1.z; o[7] = (_Float16)v1.w;
    ((half8*)out)[i] = o;
}

__global__ __launch_bounds__(256) void conv_w(const float* __restrict__ W, _Float16* __restrict__ Wt) {
    int i = blockIdx.x * 256 + threadIdx.x;
    if (i >= N_MID * NH * NH) return;
    int l = i / (NH * NH), rem = i % (NH * NH);
    int n = rem / NH, k = rem % NH;
    Wt[i] = (_Float16)W[l * NH * NH + k * NH + n];
}

// ---------------- edge sort: atomic-free bucket pipeline ----------------

__global__ __launch_bounds__(256) void bhist_k(const int* __restrict__ edst, int* __restrict__ bh) {
    __shared__ int hist[NBKT];
    const int tid = threadIdx.x;
    for (int i = tid; i < NBKT; i += 256) hist[i] = 0;
    __syncthreads();
    const int e0 = blockIdx.x * P1_EPB;
    const int e1 = min(e0 + P1_EPB, NE);
    for (int e = e0 + tid; e < e1; e += 256) atomicAdd(&hist[edst[e] >> 8], 1);
    __syncthreads();
    for (int i = tid; i < NBKT; i += 256) bh[blockIdx.x * NBKT + i] = hist[i];
}

__global__ __launch_bounds__(512) void bscan_cols(const int* __restrict__ bh, int* __restrict__ obh,
                                                  int* __restrict__ btot) {
    __shared__ int s[512];
    const int b = blockIdx.x, tid = threadIdx.x;
    int v = (tid < NP1B) ? bh[tid * NBKT + b] : 0;
    s[tid] = v;
    __syncthreads();
    for (int off = 1; off < 512; off <<= 1) {
        int t = (tid >= off) ? s[tid - off] : 0;
        __syncthreads();
        s[tid] += t;
        __syncthreads();
    }
    if (tid < NP1B) obh[tid * NBKT + b] = s[tid] - v;
    if (tid == NP1B - 1) btot[b] = s[tid];
}

__global__ __launch_bounds__(512) void bscan_top(const int* __restrict__ btot, int* __restrict__ bbase) {
    __shared__ int s[512];
    const int tid = threadIdx.x;
    int v = (tid < NBKT) ? btot[tid] : 0;
    s[tid] = v;
    __syncthreads();
    for (int off = 1; off < 512; off <<= 1) {
        int t = (tid >= off) ? s[tid - off] : 0;
        __syncthreads();
        s[tid] += t;
        __syncthreads();
    }
    if (tid < NBKT) bbase[tid] = s[tid] - v;
    if (tid == NBKT - 1) bbase[NBKT] = s[tid];   // == NE
}

__global__ __launch_bounds__(256) void p1_bucket(const int* __restrict__ esrc, const int* __restrict__ edst,
                                                 const float* __restrict__ av, const int* __restrict__ bbase,
                                                 const int* __restrict__ obh, int2* __restrict__ gbuf) {
    __shared__ int base[NBKT];
    __shared__ int rnk[NBKT];
    const int tid = threadIdx.x;
    for (int i = tid; i < NBKT; i += 256) {
        base[i] = bbase[i] + obh[blockIdx.x * NBKT + i];
        rnk[i] = 0;
    }
    __syncthreads();
    const int e0 = blockIdx.x * P1_EPB;
    const int e1 = min(e0 + P1_EPB, NE);
    for (int e = e0 + tid; e < e1; e += 256) {
        int d = edst[e];
        int b = d >> 8;
        int r = atomicAdd(&rnk[b], 1);
        gbuf[base[b] + r] = make_int2(esrc[e] | ((d & 255) << 24), __float_as_int(av[e]));
    }
}

__global__ __launch_bounds__(256) void p2_sort(const int2* __restrict__ gbuf, const int* __restrict__ bbase,
                                               int* __restrict__ rp, int2* __restrict__ rec) {
    __shared__ int hist[256];
    __shared__ int sc[256];
    __shared__ int offs[256];
    __shared__ int r2[256];
    __shared__ int2 buf[P2_CAP];
    const int b = blockIdx.x;
    const int tid = threadIdx.x;
    const int n0 = b * 256;
    const int e0 = bbase[b];
    const int e1 = bbase[b + 1];
    const int n = e1 - e0;
    hist[tid] = 0; r2[tid] = 0;
    __syncthreads();
    for (int i = tid; i < n; i += 256) atomicAdd(&hist[(unsigned)gbuf[e0 + i].x >> 24], 1);
    __syncthreads();
    sc[tid] = hist[tid];
    __syncthreads();
    for (int off = 1; off < 256; off <<= 1) {
        int t = (tid >= off) ? sc[tid - off] : 0;
        __syncthreads();
        sc[tid] += t;
        __syncthreads();
    }
    offs[tid] = sc[tid] - hist[tid];
    __syncthreads();
    if (n0 + tid < NN) rp[n0 + tid] = e0 + offs[tid];
    if (b == NBKT - 1 && tid == 0) rp[NN] = e1;
    if (n <= P2_CAP) {
        for (int i = tid; i < n; i += 256) {
            int2 rv = gbuf[e0 + i];
            int dl = (unsigned)rv.x >> 24;
            int p = offs[dl] + atomicAdd(&r2[dl], 1);
            buf[p] = make_int2(rv.x & 0x00FFFFFF, rv.y);
        }
        __syncthreads();
        for (int i = tid; i < n; i += 256) rec[e0 + i] = buf[i];
    } else {
        for (int i = tid; i < n; i += 256) {
            int2 rv = gbuf[e0 + i];
            int dl = (unsigned)rv.x >> 24;
            int p = offs[dl] + atomicAdd(&r2[dl], 1);
            rec[e0 + p] = make_int2(rv.x & 0x00FFFFFF, rv.y);
        }
    }
}

// ---------------- GEMM: S = X @ W  (f16 in/out, f32 acc, MFMA, Wt in LDS) ----------------

#define WLD 136

__global__ __launch_bounds__(256) void gemm_mfma(const _Float16* __restrict__ X, const _Float16* __restrict__ Wt,
                                                 _Float16* __restrict__ S) {
    __shared__ _Float16 wsh[128 * WLD];
    const int tid = threadIdx.x;
    // stage Wt: 16384 halves = 2048 half8-chunks, coalesced
    for (int c = tid; c < 2048; c += 256) {
        int row = c >> 4, col = c & 15;
        *(half8*)&wsh[row * WLD + col * 8] = *(const half8*)&Wt[row * 128 + col * 8];
    }

    const int wid = threadIdx.x >> 6;
    const int lane = threadIdx.x & 63;
    const int r = lane & 15, kb = lane >> 4;
    const int row0 = blockIdx.x * 64 + wid * 16;
    int arow = row0 + r;
    if (arow >= NN) arow = NN - 1;
    const _Float16* xp = X + (size_t)arow * NH + kb * 8;
    half8 a0 = *(const half8*)(xp);
    half8 a1 = *(const half8*)(xp + 32);
    half8 a2 = *(const half8*)(xp + 64);
    half8 a3 = *(const half8*)(xp + 96);
    f32x4 acc[8];
#pragma unroll
    for (int t = 0; t < 8; t++) acc[t] = (f32x4){0.f, 0.f, 0.f, 0.f};
    __syncthreads();
#pragma unroll
    for (int t = 0; t < 8; t++) {
        const _Float16* wp = wsh + (16 * t + r) * WLD + kb * 8;
        half8 b0 = *(const half8*)(wp);
        half8 b1 = *(const half8*)(wp + 32);
        half8 b2 = *(const half8*)(wp + 64);
        half8 b3 = *(const half8*)(wp + 96);
        acc[t] = __builtin_amdgcn_mfma_f32_16x16x32_f16(a0, b0, acc[t], 0, 0, 0);
        acc[t] = __builtin_amdgcn_mfma_f32_16x16x32_f16(a1, b1, acc[t], 0, 0, 0);
        acc[t] = __builtin_amdgcn_mfma_f32_16x16x32_f16(a2, b2, acc[t], 0, 0, 0);
        acc[t] = __builtin_amdgcn_mfma_f32_16x16x32_f16(a3, b3, acc[t], 0, 0, 0);
    }
    const int orow = row0 + kb * 4;
#pragma unroll
    for (int j = 0; j < 4; j++) {
        if (orow + j < NN) {
            _Float16* sp = S + (size_t)(orow + j) * NH + r;
#pragma unroll
            for (int t = 0; t < 8; t++) sp[16 * t] = (_Float16)acc[t][j];
        }
    }
}

// ---------------- SPMM (CSR) + bias + relu, f16 rows, 16-gather MLP ----------------

__global__ __launch_bounds__(256) void spmm_f16(const _Float16* __restrict__ S, const int2* __restrict__ rec,
                                                const int* __restrict__ rp, const float* __restrict__ bias,
                                                _Float16* __restrict__ Xo) {
    int node = blockIdx.x * 4 + (threadIdx.x >> 6);
    if (node >= NN) return;
    int lane = threadIdx.x & 63;
    int g = lane >> 4;        // edge group 0..3 (stride 4 over node's edges)
    int c = lane & 15;        // cols 8c..8c+7
    int beg = rp[node], end = rp[node + 1];
    float a1[8] = {0,0,0,0,0,0,0,0}, a2[8] = {0,0,0,0,0,0,0,0};
    float a3[8] = {0,0,0,0,0,0,0,0}, a4[8] = {0,0,0,0,0,0,0,0};
    int e = beg + g;
    for (; e + 12 < end; e += 16) {   // 4 edges in flight per group
        int2 rv1 = rec[e];
        int2 rv2 = rec[e + 4];
        int2 rv3 = rec[e + 8];
        int2 rv4 = rec[e + 12];
        half8 r1 = *(const half8*)&S[(size_t)rv1.x * NH + c * 8];
        half8 r2 = *(const half8*)&S[(size_t)rv2.x * NH + c * 8];
        half8 r3 = *(const half8*)&S[(size_t)rv3.x * NH + c * 8];
        half8 r4 = *(const half8*)&S[(size_t)rv4.x * NH + c * 8];
        float v1 = __int_as_float(rv1.y), v2 = __int_as_float(rv2.y);
        float v3 = __int_as_float(rv3.y), v4 = __int_as_float(rv4.y);
#pragma unroll
        for (int j = 0; j < 8; j++) {
            a1[j] = fmaf(v1, (float)r1[j], a1[j]);
            a2[j] = fmaf(v2, (float)r2[j], a2[j]);
            a3[j] = fmaf(v3, (float)r3[j], a3[j]);
            a4[j] = fmaf(v4, (float)r4[j], a4[j]);
        }
    }
    for (; e + 4 < end; e += 8) {
        int2 rv1 = rec[e];
        int2 rv2 = rec[e + 4];
        half8 r1 = *(const half8*)&S[(size_t)rv1.x * NH + c * 8];
        half8 r2 = *(const half8*)&S[(size_t)rv2.x * NH + c * 8];
        float v1 = __int_as_float(rv1.y), v2 = __int_as_float(rv2.y);
#pragma unroll
        for (int j = 0; j < 8; j++) {
            a1[j] = fmaf(v1, (float)r1[j], a1[j]);
            a2[j] = fmaf(v2, (float)r2[j], a2[j]);
        }
    }
    if (e < end) {
        int2 rv = rec[e];
        float v = __int_as_float(rv.y);
        half8 r1 = *(const half8*)&S[(size_t)rv.x * NH + c * 8];
#pragma unroll
        for (int j = 0; j < 8; j++) a1[j] = fmaf(v, (float)r1[j], a1[j]);
    }
#pragma unroll
    for (int j = 0; j < 8; j++) {
        a1[j] += a2[j] + (a3[j] + a4[j]);
        a1[j] += __shfl_xor(a1[j], 16, 64);
        a1[j] += __shfl_xor(a1[j], 32, 64);
    }
    if (g == 0) {
        float4 b0 = *(const float4*)&bias[c * 8];
        float4 b1 = *(const float4*)&bias[c * 8 + 4];
        half8 o;
        o[0] = (_Float16)fmaxf(a1[0] + b0.x, 0.f);
        o[1] = (_Float16)fmaxf(a1[1] + b0.y, 0.f);
        o[2] = (_Float16)fmaxf(a1[2] + b0.z, 0.f);
        o[3] = (_Float16)fmaxf(a1[3] + b0.w, 0.f);
        o[4] = (_Float16)fmaxf(a1[4] + b1.x, 0.f);
        o[5] = (_Float16)fmaxf(a1[5] + b1.y, 0.f);
        o[6] = (_Float16)fmaxf(a1[6] + b1.z, 0.f);
        o[7] = (_Float16)fmaxf(a1[7] + b1.w, 0.f);
        *(half8*)&Xo[(size_t)node * NH + c * 8] = o;
    }
}

// ---------------- layer 10 ----------------

__global__ __launch_bounds__(256) void dot128_f16(const _Float16* __restrict__ X, const float* __restrict__ w,
                                                  float* __restrict__ s10) {
    int node = blockIdx.x * 4 + (threadIdx.x >> 6);
    if (node >= NN) return;
    int lane = threadIdx.x & 63;
    half2v xv = *(const half2v*)&X[(size_t)node * NH + lane * 2];
    float2 wv = *(const float2*)&w[lane * 2];
    float p = (float)xv[0] * wv.x + (float)xv[1] * wv.y;
#pragma unroll
    for (int off = 32; off; off >>= 1) p += __shfl_down(p, off, 64);
    if (lane == 0) s10[node] = p;
}

__global__ __launch_bounds__(256) void spmm_scalar(const float* __restrict__ s10, const int2* __restrict__ rec,
                                                   const int* __restrict__ rp, const float* __restrict__ b10,
                                                   float* __restrict__ o10) {
    int node = blockIdx.x * 256 + threadIdx.x;
    if (node >= NN) return;
    int beg = rp[node], end = rp[node + 1];
    float a = 0.f;
    for (int e = beg; e < end; e++) {
        int2 r = rec[e];
        a = fmaf(__int_as_float(r.y), s10[r.x], a);
    }
    o10[node] = a + b10[0];
}

// ---------------- log_softmax ----------------

#define LSM_NB 240

__global__ __launch_bounds__(256) void lsm_max(const float* __restrict__ v, float* __restrict__ pmax) {
    __shared__ float s[256];
    float m = -FLT_MAX;
    for (int i = blockIdx.x * 256 + threadIdx.x; i < NN; i += LSM_NB * 256) m = fmaxf(m, v[i]);
    s[threadIdx.x] = m;
    __syncthreads();
    for (int off = 128; off; off >>= 1) {
        if (threadIdx.x < off) s[threadIdx.x] = fmaxf(s[threadIdx.x], s[threadIdx.x + off]);
        __syncthreads();
    }
    if (threadIdx.x == 0) pmax[blockIdx.x] = s[0];
}

__global__ __launch_bounds__(256) void lsm_sum(const float* __restrict__ v, const float* __restrict__ pmax,
                                               float* __restrict__ psum) {
    __shared__ float s[256];
    float m = -FLT_MAX;
    if (threadIdx.x < LSM_NB) m = pmax[threadIdx.x];
    s[threadIdx.x] = m;
    __syncthreads();
    for (int off = 128; off; off >>= 1) {
        if (threadIdx.x < off) s[threadIdx.x] = fmaxf(s[threadIdx.x], s[threadIdx.x + off]);
        __syncthreads();
    }
    float gm = s[0];
    __syncthreads();
    float sum = 0.f;
    for (int i = blockIdx.x * 256 + threadIdx.x; i < NN; i += LSM_NB * 256) sum += expf(v[i] - gm);
    s[threadIdx.x] = sum;
    __syncthreads();
    for (int off = 128; off; off >>= 1) {
        if (threadIdx.x < off) s[threadIdx.x] += s[threadIdx.x + off];
        __syncthreads();
    }
    if (threadIdx.x == 0) psum[blockIdx.x] = s[0];
}

__global__ __launch_bounds__(256) void lsm_fin(const float* __restrict__ pmax, const float* __restrict__ psum,
                                               float* __restrict__ c) {
    __shared__ float s[256];
    float m = -FLT_MAX, sum = 0.f;
    if (threadIdx.x < LSM_NB) { m = pmax[threadIdx.x]; sum = psum[threadIdx.x]; }
    s[threadIdx.x] = m;
    __syncthreads();
    for (int off = 128; off; off >>= 1) {
        if (threadIdx.x < off) s[threadIdx.x] = fmaxf(s[threadIdx.x], s[threadIdx.x + off]);
        __syncthreads();
    }
    float gm = s[0];
    __syncthreads();
    s[threadIdx.x] = sum;
    __syncthreads();
    for (int off = 128; off; off >>= 1) {
        if (threadIdx.x < off) s[threadIdx.x] += s[threadIdx.x + off];
        __syncthreads();
    }
    if (threadIdx.x == 0) c[0] = gm + logf(s[0]);
}

__global__ __launch_bounds__(256) void lsm_write(const float* __restrict__ o10, const float* __restrict__ c,
                                                 float* __restrict__ out) {
    int i = blockIdx.x * 256 + threadIdx.x;
    if (i < NN) out[i] = o10[i] - c[0];
}

// ---------------- launch ----------------

extern "C" void kernel_launch(void* const* d_in, const int* in_sizes, int n_in,
                              void* d_out, int out_size, void* d_ws, size_t ws_size,
                              hipStream_t stream) {
    const float* features = (const float*)d_in[0];
    const float* adj_vals = (const float*)d_in[1];
    const float* Ws       = (const float*)d_in[2];
    const float* bs       = (const float*)d_in[3];
    const float* W10      = (const float*)d_in[4];
    const float* b10      = (const float*)d_in[5];
    const int*   esrc     = (const int*)d_in[6];
    const int*   edst     = (const int*)d_in[7];
    float* out = (float*)d_out;

    char* ws = (char*)d_ws;
    const size_t SZH = (size_t)NN * NH * 2;          // 25.6 MB per f16 buffer
    _Float16* S_h = (_Float16*)(ws);
    _Float16* xA  = (_Float16*)(ws + SZH);
    _Float16* xB  = (_Float16*)(ws + 2 * SZH);       // f16 features live here first
    _Float16* Wt  = (_Float16*)(ws + 3 * SZH);
    char* p = ws + 3 * SZH + (size_t)N_MID * NH * NH * 2;
    int2* rec  = (int2*)p;                           // 12.8 MB
    int2* gbuf = (int2*)(p + (size_t)NE * 8);        // 12.8 MB
    int* bh    = (int*)(p + 2 * (size_t)NE * 8);     // NP1B*NBKT
    int* obh   = bh + NP1B * NBKT;                   // NP1B*NBKT
    int* btot  = obh + NP1B * NBKT;                  // NBKT
    int* bbase = btot + NBKT;                        // NBKT+1
    int* rp    = bbase + NBKT + 1;                   // NN+1
    float* s10 = (float*)(rp + NN + 1);
    float* o10 = s10 + NN;
    float* pmax = o10 + NN;
    float* psum = pmax + LSM_NB;
    float* cbuf = psum + LSM_NB;

    // prep: dtype conversions
    conv_x<<<(NN * NH / 8 + 255) / 256, 256, 0, stream>>>(features, xB);
    conv_w<<<(N_MID * NH * NH + 255) / 256, 256, 0, stream>>>(Ws, Wt);

    // edge sort + CSR build
    bhist_k<<<NP1B, 256, 0, stream>>>(edst, bh);
    bscan_cols<<<NBKT, 512, 0, stream>>>(bh, obh, btot);
    bscan_top<<<1, 512, 0, stream>>>(btot, bbase);
    p1_bucket<<<NP1B, 256, 0, stream>>>(esrc, edst, adj_vals, bbase, obh, gbuf);
    p2_sort<<<NBKT, 256, 0, stream>>>(gbuf, bbase, rp, rec);

    const _Float16* xin = xB;
    _Float16* xout = xA;
    for (int l = 0; l < N_MID; l++) {
        gemm_mfma<<<(NN + 63) / 64, 256, 0, stream>>>(xin, Wt + (size_t)l * NH * NH, S_h);
        spmm_f16<<<NN / 4, 256, 0, stream>>>(S_h, rec, rp, bs + (size_t)l * NH, xout);
        xin = xout;
        xout = (xout == xA) ? xB : xA;
    }

    dot128_f16<<<NN / 4, 256, 0, stream>>>(xin, W10, s10);
    spmm_scalar<<<(NN + 255) / 256, 256, 0, stream>>>(s10, rec, rp, b10, o10);
    lsm_max<<<LSM_NB, 256, 0, stream>>>(o10, pmax);
    lsm_sum<<<LSM_NB, 256, 0, stream>>>(o10, pmax, psum);
    lsm_fin<<<1, 256, 0, stream>>>(pmax, psum, cbuf);
    lsm_write<<<(NN + 255) / 256, 256, 0, stream>>>(o10, cbuf, out);
}

// Round 8
// 762.574 us; speedup vs baseline: 3.5202x; 1.1719x over previous
//
#include <hip/hip_runtime.h>
#include <float.h>

#define NN 100000
#define NE 1600000
#define NH 128
#define N_MID 9
#define NBKT ((NN + 255) / 256)      // 391 dst-buckets of 256 nodes
#define P1_EPB 4096                  // edges per pass-1 block
#define NP1B ((NE + P1_EPB - 1) / P1_EPB)  // 391 pass-1 blocks
#define P2_CAP 5120                  // LDS record capacity in pass 2 (avg 4092, sigma 64)

typedef _Float16 half8 __attribute__((ext_vector_type(8)));
typedef _Float16 half2v __attribute__((ext_vector_type(2)));
typedef float f32x4 __attribute__((ext_vector_type(4)));

// ---------------- dtype prep ----------------

__global__ __launch_bounds__(256) void conv_x(const float* __restrict__ in, _Float16* __restrict__ out) {
    int i = blockIdx.x * 256 + threadIdx.x;
    if (i >= NN * NH / 8) return;
    float4 v0 = ((const float4*)in)[i * 2];
    float4 v1 = ((const float4*)in)[i * 2 + 1];
    half8 o;
    o[0] = (_Float16)v0.x; o[1] = (_Float16)v0.y; o[2] = (_Float16)v0.z; o[3] = (_Float16)v0.w;
    o[4] = (_Float16)v1.x; o[5] = (_Float16)v1.y; o[6] = (_Float16)v1.z; o[7] = (_Float16)v1.w;
    ((half8*)out)[i] = o;
}

__global__ __launch_bounds__(256) void conv_w(const float* __restrict__ W, _Float16* __restrict__ Wt) {
    int i = blockIdx.x * 256 + threadIdx.x;
    if (i >= N_MID * NH * NH) return;
    int l = i / (NH * NH), rem = i % (NH * NH);
    int n = rem / NH, k = rem % NH;
    Wt[i] = (_Float16)W[l * NH * NH + k * NH + n];
}

// ---------------- edge sort: atomic-free bucket pipeline ----------------

__global__ __launch_bounds__(256) void bhist_k(const int* __restrict__ edst, int* __restrict__ bh) {
    __shared__ int hist[NBKT];
    const int tid = threadIdx.x;
    for (int i = tid; i < NBKT; i += 256) hist[i] = 0;
    __syncthreads();
    const int e0 = blockIdx.x * P1_EPB;
    const int e1 = min(e0 + P1_EPB, NE);
    for (int e = e0 + tid; e < e1; e += 256) atomicAdd(&hist[edst[e] >> 8], 1);
    __syncthreads();
    for (int i = tid; i < NBKT; i += 256) bh[blockIdx.x * NBKT + i] = hist[i];
}

__global__ __launch_bounds__(512) void bscan_cols(const int* __restrict__ bh, int* __restrict__ obh,
                                                  int* __restrict__ btot) {
    __shared__ int s[512];
    const int b = blockIdx.x, tid = threadIdx.x;
    int v = (tid < NP1B) ? bh[tid * NBKT + b] : 0;
    s[tid] = v;
    __syncthreads();
    for (int off = 1; off < 512; off <<= 1) {
        int t = (tid >= off) ? s[tid - off] : 0;
        __syncthreads();
        s[tid] += t;
        __syncthreads();
    }
    if (tid < NP1B) obh[tid * NBKT + b] = s[tid] - v;
    if (tid == NP1B - 1) btot[b] = s[tid];
}

__global__ __launch_bounds__(512) void bscan_top(const int* __restrict__ btot, int* __restrict__ bbase) {
    __shared__ int s[512];
    const int tid = threadIdx.x;
    int v = (tid < NBKT) ? btot[tid] : 0;
    s[tid] = v;
    __syncthreads();
    for (int off = 1; off < 512; off <<= 1) {
        int t = (tid >= off) ? s[tid - off] : 0;
        __syncthreads();
        s[tid] += t;
        __syncthreads();
    }
    if (tid < NBKT) bbase[tid] = s[tid] - v;
    if (tid == NBKT - 1) bbase[NBKT] = s[tid];   // == NE
}

__global__ __launch_bounds__(256) void p1_bucket(const int* __restrict__ esrc, const int* __restrict__ edst,
                                                 const float* __restrict__ av, const int* __restrict__ bbase,
                                                 const int* __restrict__ obh, int2* __restrict__ gbuf) {
    __shared__ int base[NBKT];
    __shared__ int rnk[NBKT];
    const int tid = threadIdx.x;
    for (int i = tid; i < NBKT; i += 256) {
        base[i] = bbase[i] + obh[blockIdx.x * NBKT + i];
        rnk[i] = 0;
    }
    __syncthreads();
    const int e0 = blockIdx.x * P1_EPB;
    const int e1 = min(e0 + P1_EPB, NE);
    for (int e = e0 + tid; e < e1; e += 256) {
        int d = edst[e];
        int b = d >> 8;
        int r = atomicAdd(&rnk[b], 1);
        gbuf[base[b] + r] = make_int2(esrc[e] | ((d & 255) << 24), __float_as_int(av[e]));
    }
}

__global__ __launch_bounds__(256) void p2_sort(const int2* __restrict__ gbuf, const int* __restrict__ bbase,
                                               int* __restrict__ rp, int2* __restrict__ rec) {
    __shared__ int hist[256];
    __shared__ int sc[256];
    __shared__ int offs[256];
    __shared__ int r2[256];
    __shared__ int2 buf[P2_CAP];
    const int b = blockIdx.x;
    const int tid = threadIdx.x;
    const int n0 = b * 256;
    const int e0 = bbase[b];
    const int e1 = bbase[b + 1];
    const int n = e1 - e0;
    hist[tid] = 0; r2[tid] = 0;
    __syncthreads();
    for (int i = tid; i < n; i += 256) atomicAdd(&hist[(unsigned)gbuf[e0 + i].x >> 24], 1);
    __syncthreads();
    sc[tid] = hist[tid];
    __syncthreads();
    for (int off = 1; off < 256; off <<= 1) {
        int t = (tid >= off) ? sc[tid - off] : 0;
        __syncthreads();
        sc[tid] += t;
        __syncthreads();
    }
    offs[tid] = sc[tid] - hist[tid];
    __syncthreads();
    if (n0 + tid < NN) rp[n0 + tid] = e0 + offs[tid];
    if (b == NBKT - 1 && tid == 0) rp[NN] = e1;
    if (n <= P2_CAP) {
        for (int i = tid; i < n; i += 256) {
            int2 rv = gbuf[e0 + i];
            int dl = (unsigned)rv.x >> 24;
            int p = offs[dl] + atomicAdd(&r2[dl], 1);
            buf[p] = make_int2(rv.x & 0x00FFFFFF, rv.y);
        }
        __syncthreads();
        for (int i = tid; i < n; i += 256) rec[e0 + i] = buf[i];
    } else {
        for (int i = tid; i < n; i += 256) {
            int2 rv = gbuf[e0 + i];
            int dl = (unsigned)rv.x >> 24;
            int p = offs[dl] + atomicAdd(&r2[dl], 1);
            rec[e0 + p] = make_int2(rv.x & 0x00FFFFFF, rv.y);
        }
    }
}

// ---------------- GEMM: S = X @ W  (f16 in/out, f32 acc, MFMA, Wt in LDS) ----------------

#define WLD 136

__global__ __launch_bounds__(256) void gemm_mfma(const _Float16* __restrict__ X, const _Float16* __restrict__ Wt,
                                                 _Float16* __restrict__ S) {
    __shared__ _Float16 wsh[128 * WLD];
    const int tid = threadIdx.x;
    // stage Wt: 16384 halves = 2048 half8-chunks, coalesced
    for (int c = tid; c < 2048; c += 256) {
        int row = c >> 4, col = c & 15;
        *(half8*)&wsh[row * WLD + col * 8] = *(const half8*)&Wt[row * 128 + col * 8];
    }

    const int wid = threadIdx.x >> 6;
    const int lane = threadIdx.x & 63;
    const int r = lane & 15, kb = lane >> 4;
    const int row0 = blockIdx.x * 64 + wid * 16;
    int arow = row0 + r;
    if (arow >= NN) arow = NN - 1;
    const _Float16* xp = X + (size_t)arow * NH + kb * 8;
    half8 a0 = *(const half8*)(xp);
    half8 a1 = *(const half8*)(xp + 32);
    half8 a2 = *(const half8*)(xp + 64);
    half8 a3 = *(const half8*)(xp + 96);
    f32x4 acc[8];
#pragma unroll
    for (int t = 0; t < 8; t++) acc[t] = (f32x4){0.f, 0.f, 0.f, 0.f};
    __syncthreads();
#pragma unroll
    for (int t = 0; t < 8; t++) {
        const _Float16* wp = wsh + (16 * t + r) * WLD + kb * 8;
        half8 b0 = *(const half8*)(wp);
        half8 b1 = *(const half8*)(wp + 32);
        half8 b2 = *(const half8*)(wp + 64);
        half8 b3 = *(const half8*)(wp + 96);
        acc[t] = __builtin_amdgcn_mfma_f32_16x16x32_f16(a0, b0, acc[t], 0, 0, 0);
        acc[t] = __builtin_amdgcn_mfma_f32_16x16x32_f16(a1, b1, acc[t], 0, 0, 0);
        acc[t] = __builtin_amdgcn_mfma_f32_16x16x32_f16(a2, b2, acc[t], 0, 0, 0);
        acc[t] = __builtin_amdgcn_mfma_f32_16x16x32_f16(a3, b3, acc[t], 0, 0, 0);
    }
    const int orow = row0 + kb * 4;
#pragma unroll
    for (int j = 0; j < 4; j++) {
        if (orow + j < NN) {
            _Float16* sp = S + (size_t)(orow + j) * NH + r;
#pragma unroll
            for (int t = 0; t < 8; t++) sp[16 * t] = (_Float16)acc[t][j];
        }
    }
}

// ---------------- SPMM (CSR) + bias + relu, f16 rows, 2-deep + rec prefetch ----------------

__global__ __launch_bounds__(256) void spmm_f16(const _Float16* __restrict__ S, const int2* __restrict__ rec,
                                                const int* __restrict__ rp, const float* __restrict__ bias,
                                                _Float16* __restrict__ Xo) {
    int node = blockIdx.x * 4 + (threadIdx.x >> 6);
    if (node >= NN) return;
    int lane = threadIdx.x & 63;
    int g = lane >> 4;        // edge group 0..3 (stride 4 over node's edges)
    int c = lane & 15;        // cols 8c..8c+7
    int beg = rp[node], end = rp[node + 1];
    float acc[8] = {0.f, 0.f, 0.f, 0.f, 0.f, 0.f, 0.f, 0.f};
    float acc2[8] = {0.f, 0.f, 0.f, 0.f, 0.f, 0.f, 0.f, 0.f};
    int e = beg + g;
    int2 n1 = make_int2(0, 0), n2 = make_int2(0, 0);
    if (e + 4 < end) { n1 = rec[e]; n2 = rec[e + 4]; }
    for (; e + 4 < end; e += 8) {
        int2 rv1 = n1, rv2 = n2;
        if (e + 12 < end) { n1 = rec[e + 8]; n2 = rec[e + 12]; }   // prefetch next pair
        half8 r1 = *(const half8*)&S[(size_t)rv1.x * NH + c * 8];
        half8 r2 = *(const half8*)&S[(size_t)rv2.x * NH + c * 8];
        float v1 = __int_as_float(rv1.y);
        float v2 = __int_as_float(rv2.y);
#pragma unroll
        for (int j = 0; j < 8; j++) {
            acc[j]  = fmaf(v1, (float)r1[j], acc[j]);
            acc2[j] = fmaf(v2, (float)r2[j], acc2[j]);
        }
    }
    if (e < end) {
        int2 rv = rec[e];
        float v = __int_as_float(rv.y);
        half8 r1 = *(const half8*)&S[(size_t)rv.x * NH + c * 8];
#pragma unroll
        for (int j = 0; j < 8; j++) acc[j] = fmaf(v, (float)r1[j], acc[j]);
    }
#pragma unroll
    for (int j = 0; j < 8; j++) {
        acc[j] += acc2[j];
        acc[j] += __shfl_xor(acc[j], 16, 64);
        acc[j] += __shfl_xor(acc[j], 32, 64);
    }
    if (g == 0) {
        float4 b0 = *(const float4*)&bias[c * 8];
        float4 b1 = *(const float4*)&bias[c * 8 + 4];
        half8 o;
        o[0] = (_Float16)fmaxf(acc[0] + b0.x, 0.f);
        o[1] = (_Float16)fmaxf(acc[1] + b0.y, 0.f);
        o[2] = (_Float16)fmaxf(acc[2] + b0.z, 0.f);
        o[3] = (_Float16)fmaxf(acc[3] + b0.w, 0.f);
        o[4] = (_Float16)fmaxf(acc[4] + b1.x, 0.f);
        o[5] = (_Float16)fmaxf(acc[5] + b1.y, 0.f);
        o[6] = (_Float16)fmaxf(acc[6] + b1.z, 0.f);
        o[7] = (_Float16)fmaxf(acc[7] + b1.w, 0.f);
        *(half8*)&Xo[(size_t)node * NH + c * 8] = o;
    }
}

// ---------------- layer 10 ----------------

__global__ __launch_bounds__(256) void dot128_f16(const _Float16* __restrict__ X, const float* __restrict__ w,
                                                  float* __restrict__ s10) {
    int node = blockIdx.x * 4 + (threadIdx.x >> 6);
    if (node >= NN) return;
    int lane = threadIdx.x & 63;
    half2v xv = *(const half2v*)&X[(size_t)node * NH + lane * 2];
    float2 wv = *(const float2*)&w[lane * 2];
    float p = (float)xv[0] * wv.x + (float)xv[1] * wv.y;
#pragma unroll
    for (int off = 32; off; off >>= 1) p += __shfl_down(p, off, 64);
    if (lane == 0) s10[node] = p;
}

__global__ __launch_bounds__(256) void spmm_scalar(const float* __restrict__ s10, const int2* __restrict__ rec,
                                                   const int* __restrict__ rp, const float* __restrict__ b10,
                                                   float* __restrict__ o10) {
    int node = blockIdx.x * 256 + threadIdx.x;
    if (node >= NN) return;
    int beg = rp[node], end = rp[node + 1];
    float a = 0.f;
    for (int e = beg; e < end; e++) {
        int2 r = rec[e];
        a = fmaf(__int_as_float(r.y), s10[r.x], a);
    }
    o10[node] = a + b10[0];
}

// ---------------- log_softmax ----------------

#define LSM_NB 240

__global__ __launch_bounds__(256) void lsm_max(const float* __restrict__ v, float* __restrict__ pmax) {
    __shared__ float s[256];
    float m = -FLT_MAX;
    for (int i = blockIdx.x * 256 + threadIdx.x; i < NN; i += LSM_NB * 256) m = fmaxf(m, v[i]);
    s[threadIdx.x] = m;
    __syncthreads();
    for (int off = 128; off; off >>= 1) {
        if (threadIdx.x < off) s[threadIdx.x] = fmaxf(s[threadIdx.x], s[threadIdx.x + off]);
        __syncthreads();
    }
    if (threadIdx.x == 0) pmax[blockIdx.x] = s[0];
}

__global__ __launch_bounds__(256) void lsm_sum(const float* __restrict__ v, const float* __restrict__ pmax,
                                               float* __restrict__ psum) {
    __shared__ float s[256];
    float m = -FLT_MAX;
    if (threadIdx.x < LSM_NB) m = pmax[threadIdx.x];
    s[threadIdx.x] = m;
    __syncthreads();
    for (int off = 128; off; off >>= 1) {
        if (threadIdx.x < off) s[threadIdx.x] = fmaxf(s[threadIdx.x], s[threadIdx.x + off]);
        __syncthreads();
    }
    float gm = s[0];
    __syncthreads();
    float sum = 0.f;
    for (int i = blockIdx.x * 256 + threadIdx.x; i < NN; i += LSM_NB * 256) sum += expf(v[i] - gm);
    s[threadIdx.x] = sum;
    __syncthreads();
    for (int off = 128; off; off >>= 1) {
        if (threadIdx.x < off) s[threadIdx.x] += s[threadIdx.x + off];
        __syncthreads();
    }
    if (threadIdx.x == 0) psum[blockIdx.x] = s[0];
}

__global__ __launch_bounds__(256) void lsm_fin(const float* __restrict__ pmax, const float* __restrict__ psum,
                                               float* __restrict__ c) {
    __shared__ float s[256];
    float m = -FLT_MAX, sum = 0.f;
    if (threadIdx.x < LSM_NB) { m = pmax[threadIdx.x]; sum = psum[threadIdx.x]; }
    s[threadIdx.x] = m;
    __syncthreads();
    for (int off = 128; off; off >>= 1) {
        if (threadIdx.x < off) s[threadIdx.x] = fmaxf(s[threadIdx.x], s[threadIdx.x + off]);
        __syncthreads();
    }
    float gm = s[0];
    __syncthreads();
    s[threadIdx.x] = sum;
    __syncthreads();
    for (int off = 128; off; off >>= 1) {
        if (threadIdx.x < off) s[threadIdx.x] += s[threadIdx.x + off];
        __syncthreads();
    }
    if (threadIdx.x == 0) c[0] = gm + logf(s[0]);
}

__global__ __launch_bounds__(256) void lsm_write(const float* __restrict__ o10, const float* __restrict__ c,
                                                 float* __restrict__ out) {
    int i = blockIdx.x * 256 + threadIdx.x;
    if (i < NN) out[i] = o10[i] - c[0];
}

// ---------------- launch ----------------

extern "C" void kernel_launch(void* const* d_in, const int* in_sizes, int n_in,
                              void* d_out, int out_size, void* d_ws, size_t ws_size,
                              hipStream_t stream) {
    const float* features = (const float*)d_in[0];
    const float* adj_vals = (const float*)d_in[1];
    const float* Ws       = (const float*)d_in[2];
    const float* bs       = (const float*)d_in[3];
    const float* W10      = (const float*)d_in[4];
    const float* b10      = (const float*)d_in[5];
    const int*   esrc     = (const int*)d_in[6];
    const int*   edst     = (const int*)d_in[7];
    float* out = (float*)d_out;

    char* ws = (char*)d_ws;
    const size_t SZH = (size_t)NN * NH * 2;          // 25.6 MB per f16 buffer
    _Float16* S_h = (_Float16*)(ws);
    _Float16* xA  = (_Float16*)(ws + SZH);
    _Float16* xB  = (_Float16*)(ws + 2 * SZH);       // f16 features live here first
    _Float16* Wt  = (_Float16*)(ws + 3 * SZH);
    char* p = ws + 3 * SZH + (size_t)N_MID * NH * NH * 2;
    int2* rec  = (int2*)p;                           // 12.8 MB
    int2* gbuf = (int2*)(p + (size_t)NE * 8);        // 12.8 MB
    int* bh    = (int*)(p + 2 * (size_t)NE * 8);     // NP1B*NBKT
    int* obh   = bh + NP1B * NBKT;                   // NP1B*NBKT
    int* btot  = obh + NP1B * NBKT;                  // NBKT
    int* bbase = btot + NBKT;                        // NBKT+1
    int* rp    = bbase + NBKT + 1;                   // NN+1
    float* s10 = (float*)(rp + NN + 1);
    float* o10 = s10 + NN;
    float* pmax = o10 + NN;
    float* psum = pmax + LSM_NB;
    float* cbuf = psum + LSM_NB;

    // prep: dtype conversions
    conv_x<<<(NN * NH / 8 + 255) / 256, 256, 0, stream>>>(features, xB);
    conv_w<<<(N_MID * NH * NH + 255) / 256, 256, 0, stream>>>(Ws, Wt);

    // edge sort + CSR build
    bhist_k<<<NP1B, 256, 0, stream>>>(edst, bh);
    bscan_cols<<<NBKT, 512, 0, stream>>>(bh, obh, btot);
    bscan_top<<<1, 512, 0, stream>>>(btot, bbase);
    p1_bucket<<<NP1B, 256, 0, stream>>>(esrc, edst, adj_vals, bbase, obh, gbuf);
    p2_sort<<<NBKT, 256, 0, stream>>>(gbuf, bbase, rp, rec);

    const _Float16* xin = xB;
    _Float16* xout = xA;
    for (int l = 0; l < N_MID; l++) {
        gemm_mfma<<<(NN + 63) / 64, 256, 0, stream>>>(xin, Wt + (size_t)l * NH * NH, S_h);
        spmm_f16<<<NN / 4, 256, 0, stream>>>(S_h, rec, rp, bs + (size_t)l * NH, xout);
        xin = xout;
        xout = (xout == xA) ? xB : xA;
    }

    dot128_f16<<<NN / 4, 256, 0, stream>>>(xin, W10, s10);
    spmm_scalar<<<(NN + 255) / 256, 256, 0, stream>>>(s10, rec, rp, b10, o10);
    lsm_max<<<LSM_NB, 256, 0, stream>>>(o10, pmax);
    lsm_sum<<<LSM_NB, 256, 0, stream>>>(o10, pmax, psum);
    lsm_fin<<<1, 256, 0, stream>>>(pmax, psum, cbuf);
    lsm_write<<<(NN + 255) / 256, 256, 0, stream>>>(o10, cbuf, out);
}